// Round 12
// baseline (674.480 us; speedup 1.0000x reference)
//
#include <hip/hip_runtime.h>
#include <hip/hip_bf16.h>

// ---------------------------------------------------------------------------
// SelfAttention (B=2,S=2048,D=4096, NH=32,NKV=8,HD=128, NREP=4, non-causal)
// RoPE on K and V (reference quirk), NOT on Q.
// Round 12:
//  - NEW gemm256_bk32 for the QKV projection: BK=32, LDS 64KB -> 2 blocks/CU
//    (grid 384 fully resident: no tail, cross-block stall filling).
//    Chunk-major LDS [4kc][256][8], 8 phases/iter (2 tiles), 1 load/phase,
//    gates vmcnt(2)@ph1/ph5, barrier every phase (WAR-checked per region).
//  - O-projection keeps the round-11 8-phase BK=64 kernel (proven 1-round).
//  - wq/wk/wv conversions merged into one launch.
// ---------------------------------------------------------------------------

typedef short bf16x8 __attribute__((ext_vector_type(8)));
typedef float f32x4 __attribute__((ext_vector_type(4)));

__device__ __forceinline__ void load16(const void* g, void* l) {
  __builtin_amdgcn_global_load_lds(
      (const __attribute__((address_space(1))) void*)g,
      (__attribute__((address_space(3))) void*)l, 16, 0, 0);
}

__device__ __forceinline__ f32x4 mfma16(bf16x8 a, bf16x8 b, f32x4 c) {
  return __builtin_amdgcn_mfma_f32_16x16x32_bf16(a, b, c, 0, 0, 0);
}

__device__ __forceinline__ unsigned short f2b(float f) {
  union { float f; unsigned int u; } v; v.f = f;
  unsigned int u = v.u;
  return (unsigned short)((u + 0x7fffu + ((u >> 16) & 1u)) >> 16);
}
__device__ __forceinline__ float b2f(unsigned short u) {
  union { unsigned int u; float f; } v; v.u = ((unsigned int)u) << 16;
  return v.f;
}
__device__ __forceinline__ unsigned short f2b_fast(float f) {
  __hip_bfloat16 h = __float2bfloat16(f);
  return *reinterpret_cast<unsigned short*>(&h);
}

#define QSCALE (0.08838834764831845f * 1.4426950408889634f)

// ---------------------------------------------------------------------------
__global__ __launch_bounds__(256) void cvt_f32_bf16(
    const float* __restrict__ in, unsigned short* __restrict__ out, int n4) {
  int idx = blockIdx.x * 256 + threadIdx.x;
  int stride = gridDim.x * 256;
  for (int i = idx; i < n4; i += stride) {
    float4 v = reinterpret_cast<const float4*>(in)[i];
    ushort4 o;
    o.x = f2b(v.x); o.y = f2b(v.y); o.z = f2b(v.z); o.w = f2b(v.w);
    reinterpret_cast<ushort4*>(out)[i] = o;
  }
}

// merged wq|wk|wv conversion into contiguous Wsc
__global__ __launch_bounds__(256) void cvt_w3(
    const float* __restrict__ wq, const float* __restrict__ wk,
    const float* __restrict__ wv, unsigned short* __restrict__ out) {
  const int nq = 4096 * 4096 / 4, nk = 1024 * 4096 / 4;
  const int tot = nq + 2 * nk;
  int idx = blockIdx.x * 256 + threadIdx.x;
  int stride = gridDim.x * 256;
  for (int i = idx; i < tot; i += stride) {
    int j = i;
    const float4* src;
    if (j < nq) {
      src = reinterpret_cast<const float4*>(wq);
    } else if (j < nq + nk) {
      src = reinterpret_cast<const float4*>(wk); j -= nq;
    } else {
      src = reinterpret_cast<const float4*>(wv); j -= nq + nk;
    }
    float4 v = src[j];
    ushort4 o;
    o.x = f2b(v.x); o.y = f2b(v.y); o.z = f2b(v.z); o.w = f2b(v.w);
    reinterpret_cast<ushort4*>(out)[i] = o;
  }
}

// ---------------------------------------------------------------------------
// BK=32 gemm: 256x256 tile, 8 waves (2Mx4N), per-wave 128x64, LDS 64KB
// (2 bufs x [A 16K | B 16K]), chunk-major [4kc][256 rows][8hw] per operand.
// 8 phases per iteration (2 K-tiles of 32). Stage stream (1 load/thread/ph):
//   ph1:A1(T1) ph2:B1(T1) ph3:B0(te) ph4:A0(te) ph5:A1(te) ph6:B1(te)
//   ph7:B0(to) ph8:A0(to)      (X0 = kc01, X1 = kc23)
// Gates: vmcnt(2)+barrier at ph1 and ph5; plain barrier at other phases
// (every stage targets a region fully read >=1 barrier earlier).
template <typename OutT>
__global__ __launch_bounds__(512, 2) void gemm256_bk32(
    const unsigned short* __restrict__ A, const unsigned short* __restrict__ Bw,
    OutT* __restrict__ C, int M, int N, int K, int sbl) {
  extern __shared__ char smem[];  // 65536
  const int tid = threadIdx.x;
  const int lane = tid & 63;
  const int w = tid >> 6;
  const int lr = lane & 15, lg = lane >> 4;
  const int wr = w >> 2, wc = w & 3;

  const int nbn = N >> 8;
  const int bid = blockIdx.x, nwg = gridDim.x;
  const int swz = (bid & 7) * (nwg >> 3) + (bid >> 3);  // nwg % 8 == 0
  const int bm = swz / nbn, bn = swz % nbn;

  const unsigned short* Ag = A + (size_t)bm * 256 * K;
  const unsigned short* Bg = Bw + (size_t)bn * 256 * K;

  const int arow = tid & 255;          // source row for this thread's chunk
  const int akc = tid >> 8;            // 0 or 1
  const int sd0 = (tid & ~63) * 16;    // wave-uniform LDS byte base (c0)

#define ST_A0(tt) load16(Ag + (size_t)arow * K + (tt)*32 + akc * 8,           \
                         smem + ((tt)&1) * 32768 + sd0)
#define ST_A1(tt) load16(Ag + (size_t)arow * K + (tt)*32 + (akc + 2) * 8,     \
                         smem + ((tt)&1) * 32768 + sd0 + 8192)
#define ST_B0(tt) load16(Bg + (size_t)arow * K + (tt)*32 + akc * 8,           \
                         smem + ((tt)&1) * 32768 + 16384 + sd0)
#define ST_B1(tt) load16(Bg + (size_t)arow * K + (tt)*32 + (akc + 2) * 8,     \
                         smem + ((tt)&1) * 32768 + 16384 + sd0 + 8192)
#define BAR __builtin_amdgcn_s_barrier()
#define GATE2                                                                 \
  asm volatile("s_waitcnt vmcnt(2)" ::: "memory");                            \
  __builtin_amdgcn_s_barrier();
#define LGKM0                                                                 \
  asm volatile("s_waitcnt lgkmcnt(0)" ::: "memory");                          \
  __builtin_amdgcn_sched_barrier(0);

  f32x4 acc[8][4];
#pragma unroll
  for (int m = 0; m < 8; ++m)
#pragma unroll
    for (int n = 0; n < 4; ++n) acc[m][n] = (f32x4){0.f, 0.f, 0.f, 0.f};

  // prologue = virtual ph3..ph8 of iteration -1 (te=0 -> buf0, to=1 -> buf1)
  ST_B0(0); ST_A0(0); ST_A1(0); ST_B1(0); ST_B0(1); ST_A0(1);

  const int NT = K >> 5;   // 128
  const int NI = NT >> 1;  // 64
  const int aRowB = (wr * 128 + lr) * 16;  // + lg*4096 + mf*256
  const int bRowB = (wc * 64 + lr) * 16;   // + lg*4096 + nf*256

  bf16x8 aR[4], b01[2], b23[2];

  for (int i = 0; i < NI; ++i) {
    const int T1 = 2 * i + 1;
    const int te = (2 * i + 2 < NT) ? 2 * i + 2 : 0;
    const int to = (2 * i + 3 < NT) ? 2 * i + 3 : 1;
    const char* d0A = smem;
    const char* d0B = smem + 16384;
    const char* d1A = smem + 32768;
    const char* d1B = smem + 49152;

    // ---- ph1: T0 mf0-3 x nf0-1 ----
    GATE2;
#pragma unroll
    for (int mf = 0; mf < 4; ++mf)
      aR[mf] = *(const bf16x8*)(d0A + lg * 4096 + aRowB + mf * 256);
#pragma unroll
    for (int nf = 0; nf < 2; ++nf)
      b01[nf] = *(const bf16x8*)(d0B + lg * 4096 + bRowB + nf * 256);
    ST_A1(T1);
    LGKM0;
    __builtin_amdgcn_s_setprio(1);
#pragma unroll
    for (int mf = 0; mf < 4; ++mf)
#pragma unroll
      for (int nf = 0; nf < 2; ++nf)
        acc[mf][nf] = mfma16(aR[mf], b01[nf], acc[mf][nf]);
    __builtin_amdgcn_s_setprio(0);

    // ---- ph2: T0 mf0-3 x nf2-3 ----
    BAR;
#pragma unroll
    for (int nf = 0; nf < 2; ++nf)
      b23[nf] = *(const bf16x8*)(d0B + lg * 4096 + bRowB + (2 + nf) * 256);
    ST_B1(T1);
    LGKM0;
    __builtin_amdgcn_s_setprio(1);
#pragma unroll
    for (int mf = 0; mf < 4; ++mf)
#pragma unroll
      for (int nf = 0; nf < 2; ++nf)
        acc[mf][2 + nf] = mfma16(aR[mf], b23[nf], acc[mf][2 + nf]);
    __builtin_amdgcn_s_setprio(0);

    // ---- ph3: T0 mf4-7 x nf0-1 ----
    BAR;
#pragma unroll
    for (int mf = 0; mf < 4; ++mf)
      aR[mf] = *(const bf16x8*)(d0A + lg * 4096 + aRowB + (4 + mf) * 256);
    ST_B0(te);
    LGKM0;
    __builtin_amdgcn_s_setprio(1);
#pragma unroll
    for (int mf = 0; mf < 4; ++mf)
#pragma unroll
      for (int nf = 0; nf < 2; ++nf)
        acc[4 + mf][nf] = mfma16(aR[mf], b01[nf], acc[4 + mf][nf]);
    __builtin_amdgcn_s_setprio(0);

    // ---- ph4: T0 mf4-7 x nf2-3 (no reads) ----
    BAR;
    ST_A0(te);
    __builtin_amdgcn_s_setprio(1);
#pragma unroll
    for (int mf = 0; mf < 4; ++mf)
#pragma unroll
      for (int nf = 0; nf < 2; ++nf)
        acc[4 + mf][2 + nf] = mfma16(aR[mf], b23[nf], acc[4 + mf][2 + nf]);
    __builtin_amdgcn_s_setprio(0);

    // ---- ph5: T1 mf0-3 x nf0-1 ----
    GATE2;
#pragma unroll
    for (int mf = 0; mf < 4; ++mf)
      aR[mf] = *(const bf16x8*)(d1A + lg * 4096 + aRowB + mf * 256);
#pragma unroll
    for (int nf = 0; nf < 2; ++nf)
      b01[nf] = *(const bf16x8*)(d1B + lg * 4096 + bRowB + nf * 256);
    ST_A1(te);
    LGKM0;
    __builtin_amdgcn_s_setprio(1);
#pragma unroll
    for (int mf = 0; mf < 4; ++mf)
#pragma unroll
      for (int nf = 0; nf < 2; ++nf)
        acc[mf][nf] = mfma16(aR[mf], b01[nf], acc[mf][nf]);
    __builtin_amdgcn_s_setprio(0);

    // ---- ph6: T1 mf0-3 x nf2-3 ----
    BAR;
#pragma unroll
    for (int nf = 0; nf < 2; ++nf)
      b23[nf] = *(const bf16x8*)(d1B + lg * 4096 + bRowB + (2 + nf) * 256);
    ST_B1(te);
    LGKM0;
    __builtin_amdgcn_s_setprio(1);
#pragma unroll
    for (int mf = 0; mf < 4; ++mf)
#pragma unroll
      for (int nf = 0; nf < 2; ++nf)
        acc[mf][2 + nf] = mfma16(aR[mf], b23[nf], acc[mf][2 + nf]);
    __builtin_amdgcn_s_setprio(0);

    // ---- ph7: T1 mf4-7 x nf0-1 ----
    BAR;
#pragma unroll
    for (int mf = 0; mf < 4; ++mf)
      aR[mf] = *(const bf16x8*)(d1A + lg * 4096 + aRowB + (4 + mf) * 256);
    ST_B0(to);
    LGKM0;
    __builtin_amdgcn_s_setprio(1);
#pragma unroll
    for (int mf = 0; mf < 4; ++mf)
#pragma unroll
      for (int nf = 0; nf < 2; ++nf)
        acc[4 + mf][nf] = mfma16(aR[mf], b01[nf], acc[4 + mf][nf]);
    __builtin_amdgcn_s_setprio(0);

    // ---- ph8: T1 mf4-7 x nf2-3 (no reads) ----
    BAR;
    ST_A0(to);
    __builtin_amdgcn_s_setprio(1);
#pragma unroll
    for (int mf = 0; mf < 4; ++mf)
#pragma unroll
      for (int nf = 0; nf < 2; ++nf)
        acc[4 + mf][2 + nf] = mfma16(aR[mf], b23[nf], acc[4 + mf][2 + nf]);
    __builtin_amdgcn_s_setprio(0);
  }
#undef ST_A0
#undef ST_A1
#undef ST_B0
#undef ST_B1
#undef BAR
#undef GATE2
#undef LGKM0

  const float cscale = (bn < sbl) ? QSCALE : 1.0f;
#pragma unroll
  for (int mf = 0; mf < 8; ++mf)
#pragma unroll
    for (int nf = 0; nf < 4; ++nf)
#pragma unroll
      for (int r = 0; r < 4; ++r) {
        int rowc = bm * 256 + wr * 128 + mf * 16 + lg * 4 + r;
        int colc = bn * 256 + wc * 64 + nf * 16 + lr;
        float v = acc[mf][nf][r] * cscale;
        if constexpr (sizeof(OutT) == 2)
          C[(size_t)rowc * N + colc] = (OutT)f2b(v);
        else
          C[(size_t)rowc * N + colc] = v;
      }
}

// ---------------------------------------------------------------------------
// Round-11 BK=64 8-phase gemm (verbatim) — used for the O projection.
template <typename OutT>
__global__ __launch_bounds__(512, 2) void gemm256(
    const unsigned short* __restrict__ A, const unsigned short* __restrict__ Bw,
    OutT* __restrict__ C, int M, int N, int K, int sbl) {
  extern __shared__ char smem[];  // 131072
  const int tid = threadIdx.x;
  const int lane = tid & 63;
  const int w = tid >> 6;
  const int lr = lane & 15, lg = lane >> 4;
  const int wr = w >> 2, wc = w & 3;

  const int nbn = N >> 8;
  const int bid = blockIdx.x, nwg = gridDim.x;
  const int swz = (bid & 7) * (nwg >> 3) + (bid >> 3);
  const int bm = swz / nbn, bn = swz % nbn;

  const unsigned short* Ag = A + (size_t)bm * 256 * K;
  const unsigned short* Bg = Bw + (size_t)bn * 256 * K;

  int aoffs[4], boffs[4], sdst[4];
#pragma unroll
  for (int j = 0; j < 4; ++j) {
    const int c = tid + j * 512;
    const int u = c >> 3;
    const int slot = ((c & 7) ^ (u & 7)) << 3;
    aoffs[j] = u * K + slot;
    const int br = ((u & 127) >> 5) * 64 + (u >> 7) * 32 + (u & 31);
    boffs[j] = br * K + slot;
    sdst[j] = ((tid & ~63) << 4) + j * 8192;
  }

#define ST_A(hh, tt)                                                          \
  {                                                                           \
    char* d = smem + (((tt)&1) * 65536);                                      \
    load16(Ag + aoffs[(hh)] + ((tt) << 6), d + sdst[(hh)]);                   \
    load16(Ag + aoffs[(hh) + 2] + ((tt) << 6), d + sdst[(hh) + 2]);           \
  }
#define ST_B(hh, tt)                                                          \
  {                                                                           \
    char* d = smem + (((tt)&1) * 65536) + 32768;                              \
    load16(Bg + boffs[(hh)*2] + ((tt) << 6), d + sdst[(hh)*2]);               \
    load16(Bg + boffs[(hh)*2 + 1] + ((tt) << 6), d + sdst[(hh)*2 + 1]);       \
  }
#define GATE10                                                                \
  asm volatile("s_waitcnt vmcnt(10)" ::: "memory");                           \
  __builtin_amdgcn_s_barrier();
#define LGKM0                                                                 \
  asm volatile("s_waitcnt lgkmcnt(0)" ::: "memory");                          \
  __builtin_amdgcn_sched_barrier(0);

  f32x4 acc[8][4];
#pragma unroll
  for (int m = 0; m < 8; ++m)
#pragma unroll
    for (int n = 0; n < 4; ++n) acc[m][n] = (f32x4){0.f, 0.f, 0.f, 0.f};

  ST_A(0, 0); ST_B(0, 0); ST_B(1, 0); ST_A(1, 0);
  ST_A(0, 1); ST_B(0, 1); ST_B(1, 1);

  const int NT = K >> 6;
  const int NI = NT >> 1;
  const int xr = (lr & 7) << 4;
  const int aBase = (wr * 128 + lr) * 128;
  const int bBase = (wc * 32 + lr) * 128;
  const int col0 = (lg * 16) ^ xr;
  const int col1 = (64 + lg * 16) ^ xr;

  bf16x8 aR[4][2], b01[2][2], b23[2][2];

  for (int i = 0; i < NI; ++i) {
    const int T1 = 2 * i + 1;
    const int te = (2 * i + 2 < NT) ? 2 * i + 2 : 0;
    const int to = (2 * i + 3 < NT) ? 2 * i + 3 : 1;
    const char* d0 = smem;
    const char* d1 = smem + 65536;

    GATE10;
#pragma unroll
    for (int mf = 0; mf < 4; ++mf) {
      aR[mf][0] = *(const bf16x8*)(d0 + aBase + mf * 2048 + col0);
      aR[mf][1] = *(const bf16x8*)(d0 + aBase + mf * 2048 + col1);
    }
#pragma unroll
    for (int nf = 0; nf < 2; ++nf) {
      b01[nf][0] = *(const bf16x8*)(d0 + 32768 + bBase + nf * 2048 + col0);
      b01[nf][1] = *(const bf16x8*)(d0 + 32768 + bBase + nf * 2048 + col1);
    }
    ST_A(1, T1);
    LGKM0;
    __builtin_amdgcn_s_setprio(1);
#pragma unroll
    for (int mf = 0; mf < 4; ++mf)
#pragma unroll
      for (int nf = 0; nf < 2; ++nf) {
        acc[mf][nf] = mfma16(aR[mf][0], b01[nf][0], acc[mf][nf]);
        acc[mf][nf] = mfma16(aR[mf][1], b01[nf][1], acc[mf][nf]);
      }
    __builtin_amdgcn_s_setprio(0);

    GATE10;
#pragma unroll
    for (int nf = 0; nf < 2; ++nf) {
      b23[nf][0] = *(const bf16x8*)(d0 + 32768 + 16384 + bBase + nf * 2048 + col0);
      b23[nf][1] = *(const bf16x8*)(d0 + 32768 + 16384 + bBase + nf * 2048 + col1);
    }
    ST_A(0, te);
    LGKM0;
    __builtin_amdgcn_s_setprio(1);
#pragma unroll
    for (int mf = 0; mf < 4; ++mf)
#pragma unroll
      for (int nf = 0; nf < 2; ++nf) {
        acc[mf][2 + nf] = mfma16(aR[mf][0], b23[nf][0], acc[mf][2 + nf]);
        acc[mf][2 + nf] = mfma16(aR[mf][1], b23[nf][1], acc[mf][2 + nf]);
      }
    __builtin_amdgcn_s_setprio(0);

    GATE10;
#pragma unroll
    for (int mf = 0; mf < 4; ++mf) {
      aR[mf][0] = *(const bf16x8*)(d0 + aBase + (4 + mf) * 2048 + col0);
      aR[mf][1] = *(const bf16x8*)(d0 + aBase + (4 + mf) * 2048 + col1);
    }
    ST_B(0, te);
    LGKM0;
    __builtin_amdgcn_s_setprio(1);
#pragma unroll
    for (int mf = 0; mf < 4; ++mf)
#pragma unroll
      for (int nf = 0; nf < 2; ++nf) {
        acc[4 + mf][nf] = mfma16(aR[mf][0], b01[nf][0], acc[4 + mf][nf]);
        acc[4 + mf][nf] = mfma16(aR[mf][1], b01[nf][1], acc[4 + mf][nf]);
      }
    __builtin_amdgcn_s_setprio(0);

    ST_B(1, te);
    __builtin_amdgcn_s_setprio(1);
#pragma unroll
    for (int mf = 0; mf < 4; ++mf)
#pragma unroll
      for (int nf = 0; nf < 2; ++nf) {
        acc[4 + mf][2 + nf] = mfma16(aR[mf][0], b23[nf][0], acc[4 + mf][2 + nf]);
        acc[4 + mf][2 + nf] = mfma16(aR[mf][1], b23[nf][1], acc[4 + mf][2 + nf]);
      }
    __builtin_amdgcn_s_setprio(0);

    GATE10;
#pragma unroll
    for (int mf = 0; mf < 4; ++mf) {
      aR[mf][0] = *(const bf16x8*)(d1 + aBase + mf * 2048 + col0);
      aR[mf][1] = *(const bf16x8*)(d1 + aBase + mf * 2048 + col1);
    }
#pragma unroll
    for (int nf = 0; nf < 2; ++nf) {
      b01[nf][0] = *(const bf16x8*)(d1 + 32768 + bBase + nf * 2048 + col0);
      b01[nf][1] = *(const bf16x8*)(d1 + 32768 + bBase + nf * 2048 + col1);
    }
    ST_A(1, te);
    LGKM0;
    __builtin_amdgcn_s_setprio(1);
#pragma unroll
    for (int mf = 0; mf < 4; ++mf)
#pragma unroll
      for (int nf = 0; nf < 2; ++nf) {
        acc[mf][nf] = mfma16(aR[mf][0], b01[nf][0], acc[mf][nf]);
        acc[mf][nf] = mfma16(aR[mf][1], b01[nf][1], acc[mf][nf]);
      }
    __builtin_amdgcn_s_setprio(0);

    GATE10;
#pragma unroll
    for (int nf = 0; nf < 2; ++nf) {
      b23[nf][0] = *(const bf16x8*)(d1 + 32768 + 16384 + bBase + nf * 2048 + col0);
      b23[nf][1] = *(const bf16x8*)(d1 + 32768 + 16384 + bBase + nf * 2048 + col1);
    }
    ST_A(0, to);
    LGKM0;
    __builtin_amdgcn_s_setprio(1);
#pragma unroll
    for (int mf = 0; mf < 4; ++mf)
#pragma unroll
      for (int nf = 0; nf < 2; ++nf) {
        acc[mf][2 + nf] = mfma16(aR[mf][0], b23[nf][0], acc[mf][2 + nf]);
        acc[mf][2 + nf] = mfma16(aR[mf][1], b23[nf][1], acc[mf][2 + nf]);
      }
    __builtin_amdgcn_s_setprio(0);

    GATE10;
#pragma unroll
    for (int mf = 0; mf < 4; ++mf) {
      aR[mf][0] = *(const bf16x8*)(d1 + aBase + (4 + mf) * 2048 + col0);
      aR[mf][1] = *(const bf16x8*)(d1 + aBase + (4 + mf) * 2048 + col1);
    }
    ST_B(0, to);
    LGKM0;
    __builtin_amdgcn_s_setprio(1);
#pragma unroll
    for (int mf = 0; mf < 4; ++mf)
#pragma unroll
      for (int nf = 0; nf < 2; ++nf) {
        acc[4 + mf][nf] = mfma16(aR[mf][0], b01[nf][0], acc[4 + mf][nf]);
        acc[4 + mf][nf] = mfma16(aR[mf][1], b01[nf][1], acc[4 + mf][nf]);
      }
    __builtin_amdgcn_s_setprio(0);

    ST_B(1, to);
    __builtin_amdgcn_s_setprio(1);
#pragma unroll
    for (int mf = 0; mf < 4; ++mf)
#pragma unroll
      for (int nf = 0; nf < 2; ++nf) {
        acc[4 + mf][2 + nf] = mfma16(aR[mf][0], b23[nf][0], acc[4 + mf][2 + nf]);
        acc[4 + mf][2 + nf] = mfma16(aR[mf][1], b23[nf][1], acc[4 + mf][2 + nf]);
      }
    __builtin_amdgcn_s_setprio(0);
  }
#undef ST_A
#undef ST_B
#undef GATE10
#undef LGKM0

  const float cscale = (bn < sbl) ? QSCALE : 1.0f;
#pragma unroll
  for (int mf = 0; mf < 8; ++mf)
#pragma unroll
    for (int nf = 0; nf < 4; ++nf)
#pragma unroll
      for (int r = 0; r < 4; ++r) {
        int rowc = bm * 256 + wr * 128 + mf * 16 + lg * 4 + r;
        int colc = bn * 256 + wc * 64 + nf * 16 + lr;
        float v = acc[mf][nf][r] * cscale;
        if constexpr (sizeof(OutT) == 2)
          C[(size_t)rowc * N + colc] = (OutT)f2b(v);
        else
          C[(size_t)rowc * N + colc] = v;
      }
}

// ---------------------------------------------------------------------------
// RoPE on K and V read from fused XQKV (row stride 6144; K col 4096+, V 5120+).
__global__ __launch_bounds__(256) void rope_kv(
    const unsigned short* __restrict__ XQKV,
    const float* __restrict__ fc, const float* __restrict__ fs,
    unsigned short* __restrict__ Kr, unsigned short* __restrict__ Vt) {
  __shared__ unsigned short Vl[128][66];
  const int t = threadIdx.x;
  const int bid = blockIdx.x;  // bkv*32 + stile
  const int stile = bid & 31, bkv = bid >> 5;
  const int b = bkv >> 3, kvh = bkv & 7;
  const int s0 = stile * 64;
  const int l = t & 63;
  const int jrow = t >> 6;

  for (int j = 0; j < 16; ++j) {
    int s = s0 + j * 4 + jrow;
    ushort2 v = *(const ushort2*)(XQKV + (size_t)(b * 2048 + s) * 6144 + 4096 +
                                  kvh * 128 + 2 * l);
    float c = fc[s * 64 + l], sn = fs[s * 64 + l];
    float xr = b2f(v.x), xi = b2f(v.y);
    ushort2 o;
    o.x = f2b(xr * c - xi * sn);
    o.y = f2b(xr * sn + xi * c);
    *(ushort2*)(Kr + ((size_t)bkv * 2048 + s) * 128 + 2 * l) = o;
  }
  for (int j = 0; j < 16; ++j) {
    int ss = j * 4 + jrow;
    int s = s0 + ss;
    ushort2 v = *(const ushort2*)(XQKV + (size_t)(b * 2048 + s) * 6144 + 5120 +
                                  kvh * 128 + 2 * l);
    float c = fc[s * 64 + l], sn = fs[s * 64 + l];
    float xr = b2f(v.x), xi = b2f(v.y);
    Vl[2 * l][ss] = f2b(xr * c - xi * sn);
    Vl[2 * l + 1][ss] = f2b(xr * sn + xi * c);
  }
  __syncthreads();
  const int d = t >> 1, half = t & 1;
  unsigned short* vdst = Vt + ((size_t)bkv * 128 + d) * 2048 + s0 + half * 32;
#pragma unroll
  for (int e = 0; e < 32; e += 4) {
    ushort4 pk;
    pk.x = Vl[d][half * 32 + e];
    pk.y = Vl[d][half * 32 + e + 1];
    pk.z = Vl[d][half * 32 + e + 2];
    pk.w = Vl[d][half * 32 + e + 3];
    *(ushort4*)(vdst + e) = pk;
  }
}

// ---------------------------------------------------------------------------
// Flash attention (round-10 kernel, unchanged). Grid 512; 4 waves x 64 q-rows.
__global__ __launch_bounds__(256, 2) void attn_fwd(
    const unsigned short* __restrict__ XQ, const unsigned short* __restrict__ Kr,
    const unsigned short* __restrict__ Vt, unsigned short* __restrict__ AO) {
  extern __shared__ char smem[];  // 49152
  char* Ksm = smem;                                      // [2][8192]
  char* Vsm = smem + 16384;                              // [2][8192]
  unsigned short* Ps = (unsigned short*)(smem + 32768);  // [4][4][64][8]
  const int t = threadIdx.x;
  const int lane = t & 63, w = t >> 6;
  const int lr = lane & 15, lg = lane >> 4;

  const int bid = blockIdx.x;
  const int nwg = gridDim.x;  // 512
  const int swz = (bid & 7) * (nwg >> 3) + (bid >> 3);
  const int qt = swz & 7;
  const int bh = swz >> 3;
  const int b = bh >> 5, h = bh & 31;
  const int bkv = b * 8 + (h >> 2);

  bf16x8 qf[4][4];
#pragma unroll
  for (int q4 = 0; q4 < 4; ++q4) {
    const unsigned short* qp =
        XQ + ((size_t)(b * 2048 + qt * 256 + w * 64 + q4 * 16 + lr)) * 6144 +
        h * 128 + lg * 8;
#pragma unroll
    for (int dc = 0; dc < 4; ++dc) qf[q4][dc] = *(const bf16x8*)(qp + dc * 32);
  }

  f32x4 acc[4][8];
#pragma unroll
  for (int q4 = 0; q4 < 4; ++q4)
#pragma unroll
    for (int i = 0; i < 8; ++i) acc[q4][i] = (f32x4){0.f, 0.f, 0.f, 0.f};
  float l_[4][4];
#pragma unroll
  for (int q4 = 0; q4 < 4; ++q4)
#pragma unroll
    for (int r = 0; r < 4; ++r) l_[q4][r] = 0.f;

  const unsigned short* Kbase = Kr + (size_t)bkv * 2048 * 128;
  const unsigned short* Vbase = Vt + (size_t)bkv * 128 * 2048;

  const int c0 = t, c1 = t + 256;
  const int kK0 = c0 & 31, dC0 = c0 >> 5;
  const int kK1 = c1 & 31, dC1 = c1 >> 5;
  const int vD0 = c0 & 127, vKc0 = c0 >> 7;
  const int vD1 = c1 & 127, vKc1 = c1 >> 7;
  const int dstb0 = (c0 & ~63) * 16;
  const int dstb1 = (c1 & ~63) * 16;

#define STAGE_KV(bufi, kt)                                                     \
  {                                                                            \
    char* kd = Ksm + (bufi)*8192;                                              \
    char* vd = Vsm + (bufi)*8192;                                              \
    load16(Kbase + (size_t)((kt)*32 + kK0) * 128 + dC0 * 8, kd + dstb0);       \
    load16(Kbase + (size_t)((kt)*32 + kK1) * 128 + dC1 * 8, kd + dstb1);       \
    load16(Vbase + (size_t)vD0 * 2048 + (kt)*32 + vKc0 * 8, vd + dstb0);       \
    load16(Vbase + (size_t)vD1 * 2048 + (kt)*32 + vKc1 * 8, vd + dstb1);       \
  }

  STAGE_KV(0, 0);
  asm volatile("s_waitcnt vmcnt(0)" ::: "memory");
  __builtin_amdgcn_s_barrier();

  unsigned short* Pw = Ps + w * 2048;              // [4 kc][64 q][8]
  const int pbase = (lr >> 3) * 512 + (lr & 7);    // halfword offset

  for (int kt = 0; kt < 64; ++kt) {
    const int cur = kt & 1;
    if (kt < 63) STAGE_KV(cur ^ 1, kt + 1);

    const char* Kc = Ksm + cur * 8192;
    const char* Vc = Vsm + cur * 8192;

#pragma unroll
    for (int nf = 0; nf < 2; ++nf) {
      f32x4 s[4];
#pragma unroll
      for (int q4 = 0; q4 < 4; ++q4) s[q4] = (f32x4){0.f, 0.f, 0.f, 0.f};
#pragma unroll
      for (int dc = 0; dc < 4; ++dc) {
        bf16x8 kf =
            *(const bf16x8*)(Kc + ((dc * 4 + lg) * 32 + nf * 16 + lr) * 16);
#pragma unroll
        for (int q4 = 0; q4 < 4; ++q4) s[q4] = mfma16(qf[q4][dc], kf, s[q4]);
      }
      const int pb = pbase + nf * 1024;  // kc = nf*2 + (lr>>3)
#pragma unroll
      for (int q4 = 0; q4 < 4; ++q4)
#pragma unroll
        for (int r = 0; r < 4; ++r) {
          float p = __builtin_amdgcn_exp2f(s[q4][r]);
          l_[q4][r] += p;
          Pw[pb + (q4 * 16 + lg * 4 + r) * 8] = f2b_fast(p);
        }
    }

    bf16x8 pf[4];
#pragma unroll
    for (int q4 = 0; q4 < 4; ++q4)
      pf[q4] = *(const bf16x8*)(Pw + lg * 512 + (q4 * 16 + lr) * 8);
#pragma unroll
    for (int dt = 0; dt < 8; ++dt) {
      bf16x8 vf = *(const bf16x8*)(Vc + (lg * 128 + dt * 16 + lr) * 16);
#pragma unroll
      for (int q4 = 0; q4 < 4; ++q4)
        acc[q4][dt] = mfma16(pf[q4], vf, acc[q4][dt]);
    }

    asm volatile("s_waitcnt vmcnt(0)" ::: "memory");
    __builtin_amdgcn_s_barrier();
  }
#undef STAGE_KV

#pragma unroll
  for (int q4 = 0; q4 < 4; ++q4)
#pragma unroll
    for (int r = 0; r < 4; ++r) {
#pragma unroll
      for (int o = 1; o < 16; o <<= 1) l_[q4][r] += __shfl_xor(l_[q4][r], o);
    }

#pragma unroll
  for (int q4 = 0; q4 < 4; ++q4)
#pragma unroll
    for (int r = 0; r < 4; ++r) {
      float inv = 1.f / l_[q4][r];
      size_t rowb =
          ((size_t)(b * 2048 + qt * 256 + w * 64 + q4 * 16 + lg * 4 + r)) * 4096 +
          h * 128;
#pragma unroll
      for (int dt = 0; dt < 8; ++dt)
        AO[rowb + dt * 16 + lr] = f2b_fast(acc[q4][dt][r] * inv);
    }
}

// ---------------------------------------------------------------------------
extern "C" void kernel_launch(void* const* d_in, const int* in_sizes, int n_in,
                              void* d_out, int out_size, void* d_ws, size_t ws_size,
                              hipStream_t stream) {
  const float* x  = (const float*)d_in[0];
  const float* fc = (const float*)d_in[2];
  const float* fs = (const float*)d_in[3];
  const float* wq = (const float*)d_in[4];
  const float* wk = (const float*)d_in[5];
  const float* wv = (const float*)d_in[6];
  const float* wo = (const float*)d_in[7];

  const size_t MB = 1024ull * 1024ull;
  char* ws = (char*)d_ws;
  unsigned short* Xb   = (unsigned short*)(ws);           // 32MB, dead after QKV gemm
  unsigned short* Wsc  = (unsigned short*)(ws + 32 * MB); // 48MB (wq|wk|wv), later wo
  unsigned short* Kr   = (unsigned short*)(ws);           // [0,8) reuse Xb
  unsigned short* Vt   = (unsigned short*)(ws + 8 * MB);  // [8,16)
  unsigned short* AO   = (unsigned short*)(ws + 80 * MB); // 32MB
  unsigned short* XQKV = (unsigned short*)d_out;          // 48MB of 64MB d_out

  (void)hipFuncSetAttribute((const void*)gemm256_bk32<unsigned short>,
                            hipFuncAttributeMaxDynamicSharedMemorySize, 65536);
  (void)hipFuncSetAttribute((const void*)gemm256<float>,
                            hipFuncAttributeMaxDynamicSharedMemorySize, 131072);
  (void)hipFuncSetAttribute((const void*)attn_fwd,
                            hipFuncAttributeMaxDynamicSharedMemorySize, 49152);

  dim3 blk(256);
  dim3 blk512(512);
  cvt_f32_bf16<<<2048, blk, 0, stream>>>(x, Xb, (2 * 2048 * 4096) / 4);
  cvt_w3<<<2048, blk, 0, stream>>>(wq, wk, wv, Wsc);
  gemm256_bk32<unsigned short><<<384, blk512, 65536, stream>>>(
      Xb, Wsc, XQKV, 4096, 6144, 4096, /*sbl=*/16);
  rope_kv<<<512, blk, 0, stream>>>(XQKV, fc, fs, Kr, Vt);
  attn_fwd<<<512, blk, 49152, stream>>>(XQKV, Kr, Vt, AO);
  cvt_f32_bf16<<<2048, blk, 0, stream>>>(wo, Wsc, (4096 * 4096) / 4);
  gemm256<float><<<256, blk512, 131072, stream>>>(
      AO, Wsc, (float*)d_out, 4096, 4096, 4096, /*sbl=*/0);
}

// Round 13
// 542.490 us; speedup vs baseline: 1.2433x; 1.2433x over previous
//
#include <hip/hip_runtime.h>
#include <hip/hip_bf16.h>

// ---------------------------------------------------------------------------
// SelfAttention (B=2,S=2048,D=4096, NH=32,NKV=8,HD=128, NREP=4, non-causal)
// RoPE on K and V (reference quirk), NOT on Q.
// Round 13: revert to the round-11 measured-best kernels (gemm256 BK=64
// 8-phase vmcnt(10); attn 4x64q; rope) and keep only round-12's safe win:
// merged wq|wk|wv conversion (cvt_w3, one launch instead of three).
// ---------------------------------------------------------------------------

typedef short bf16x8 __attribute__((ext_vector_type(8)));
typedef float f32x4 __attribute__((ext_vector_type(4)));

__device__ __forceinline__ void load16(const void* g, void* l) {
  __builtin_amdgcn_global_load_lds(
      (const __attribute__((address_space(1))) void*)g,
      (__attribute__((address_space(3))) void*)l, 16, 0, 0);
}

__device__ __forceinline__ f32x4 mfma16(bf16x8 a, bf16x8 b, f32x4 c) {
  return __builtin_amdgcn_mfma_f32_16x16x32_bf16(a, b, c, 0, 0, 0);
}

__device__ __forceinline__ unsigned short f2b(float f) {
  union { float f; unsigned int u; } v; v.f = f;
  unsigned int u = v.u;
  return (unsigned short)((u + 0x7fffu + ((u >> 16) & 1u)) >> 16);
}
__device__ __forceinline__ float b2f(unsigned short u) {
  union { unsigned int u; float f; } v; v.u = ((unsigned int)u) << 16;
  return v.f;
}
__device__ __forceinline__ unsigned short f2b_fast(float f) {
  __hip_bfloat16 h = __float2bfloat16(f);
  return *reinterpret_cast<unsigned short*>(&h);
}

#define QSCALE (0.08838834764831845f * 1.4426950408889634f)

// ---------------------------------------------------------------------------
__global__ __launch_bounds__(256) void cvt_f32_bf16(
    const float* __restrict__ in, unsigned short* __restrict__ out, int n4) {
  int idx = blockIdx.x * 256 + threadIdx.x;
  int stride = gridDim.x * 256;
  for (int i = idx; i < n4; i += stride) {
    float4 v = reinterpret_cast<const float4*>(in)[i];
    ushort4 o;
    o.x = f2b(v.x); o.y = f2b(v.y); o.z = f2b(v.z); o.w = f2b(v.w);
    reinterpret_cast<ushort4*>(out)[i] = o;
  }
}

// merged wq|wk|wv conversion into contiguous Wsc
__global__ __launch_bounds__(256) void cvt_w3(
    const float* __restrict__ wq, const float* __restrict__ wk,
    const float* __restrict__ wv, unsigned short* __restrict__ out) {
  const int nq = 4096 * 4096 / 4, nk = 1024 * 4096 / 4;
  const int tot = nq + 2 * nk;
  int idx = blockIdx.x * 256 + threadIdx.x;
  int stride = gridDim.x * 256;
  for (int i = idx; i < tot; i += stride) {
    int j = i;
    const float4* src;
    if (j < nq) {
      src = reinterpret_cast<const float4*>(wq);
    } else if (j < nq + nk) {
      src = reinterpret_cast<const float4*>(wk); j -= nq;
    } else {
      src = reinterpret_cast<const float4*>(wv); j -= nq + nk;
    }
    float4 v = src[j];
    ushort4 o;
    o.x = f2b(v.x); o.y = f2b(v.y); o.z = f2b(v.z); o.w = f2b(v.w);
    reinterpret_cast<ushort4*>(out)[i] = o;
  }
}

// ---------------------------------------------------------------------------
// Round-11 gemm256 (verbatim): 256x256 tile, BK=64, 8 waves (2Mx4N),
// per-wave 128x64. LDS: dbuf0 @0 (A 32K | B 32K), dbuf1 @64K; rows of 64hw,
// k-slot XOR swizzle by (row&7); B rows permuted so halves align with
// nf-phases. 8 phases x 16 MFMA per 2 K-tiles; half-tile staging, uniform
// vmcnt(10)+barrier gates; wrap-staging keeps the stream uniform at the end.
template <typename OutT>
__global__ __launch_bounds__(512, 2) void gemm256(
    const unsigned short* __restrict__ A, const unsigned short* __restrict__ Bw,
    OutT* __restrict__ C, int M, int N, int K, int sbl) {
  extern __shared__ char smem[];  // 131072
  const int tid = threadIdx.x;
  const int lane = tid & 63;
  const int w = tid >> 6;
  const int lr = lane & 15, lg = lane >> 4;
  const int wr = w >> 2, wc = w & 3;

  const int nbn = N >> 8;
  const int bid = blockIdx.x, nwg = gridDim.x;
  const int swz = (bid & 7) * (nwg >> 3) + (bid >> 3);  // nwg % 8 == 0
  const int bm = swz / nbn, bn = swz % nbn;

  const unsigned short* Ag = A + (size_t)bm * 256 * K;
  const unsigned short* Bg = Bw + (size_t)bn * 256 * K;

  int aoffs[4], boffs[4], sdst[4];
#pragma unroll
  for (int j = 0; j < 4; ++j) {
    const int c = tid + j * 512;
    const int u = c >> 3;
    const int slot = ((c & 7) ^ (u & 7)) << 3;
    aoffs[j] = u * K + slot;
    const int br = ((u & 127) >> 5) * 64 + (u >> 7) * 32 + (u & 31);
    boffs[j] = br * K + slot;
    sdst[j] = ((tid & ~63) << 4) + j * 8192;
  }

#define ST_A(hh, tt)                                                          \
  {                                                                           \
    char* d = smem + (((tt)&1) * 65536);                                      \
    load16(Ag + aoffs[(hh)] + ((tt) << 6), d + sdst[(hh)]);                   \
    load16(Ag + aoffs[(hh) + 2] + ((tt) << 6), d + sdst[(hh) + 2]);           \
  }
#define ST_B(hh, tt)                                                          \
  {                                                                           \
    char* d = smem + (((tt)&1) * 65536) + 32768;                              \
    load16(Bg + boffs[(hh)*2] + ((tt) << 6), d + sdst[(hh)*2]);               \
    load16(Bg + boffs[(hh)*2 + 1] + ((tt) << 6), d + sdst[(hh)*2 + 1]);       \
  }
#define GATE10                                                                \
  asm volatile("s_waitcnt vmcnt(10)" ::: "memory");                           \
  __builtin_amdgcn_s_barrier();
#define LGKM0                                                                 \
  asm volatile("s_waitcnt lgkmcnt(0)" ::: "memory");                          \
  __builtin_amdgcn_sched_barrier(0);

  f32x4 acc[8][4];
#pragma unroll
  for (int m = 0; m < 8; ++m)
#pragma unroll
    for (int n = 0; n < 4; ++n) acc[m][n] = (f32x4){0.f, 0.f, 0.f, 0.f};

  // prologue: 7 halves in stream order (virtual prev-iteration ph2..ph8)
  ST_A(0, 0); ST_B(0, 0); ST_B(1, 0); ST_A(1, 0);
  ST_A(0, 1); ST_B(0, 1); ST_B(1, 1);

  const int NT = K >> 6;
  const int NI = NT >> 1;
  const int xr = (lr & 7) << 4;
  const int aBase = (wr * 128 + lr) * 128;
  const int bBase = (wc * 32 + lr) * 128;
  const int col0 = (lg * 16) ^ xr;
  const int col1 = (64 + lg * 16) ^ xr;

  bf16x8 aR[4][2], b01[2][2], b23[2][2];

  for (int i = 0; i < NI; ++i) {
    const int T1 = 2 * i + 1;
    const int te = (2 * i + 2 < NT) ? 2 * i + 2 : 0;
    const int to = (2 * i + 3 < NT) ? 2 * i + 3 : 1;
    const char* d0 = smem;
    const char* d1 = smem + 65536;

    // ---- ph1: T0 mf0-3 x nf0-1 ----
    GATE10;
#pragma unroll
    for (int mf = 0; mf < 4; ++mf) {
      aR[mf][0] = *(const bf16x8*)(d0 + aBase + mf * 2048 + col0);
      aR[mf][1] = *(const bf16x8*)(d0 + aBase + mf * 2048 + col1);
    }
#pragma unroll
    for (int nf = 0; nf < 2; ++nf) {
      b01[nf][0] = *(const bf16x8*)(d0 + 32768 + bBase + nf * 2048 + col0);
      b01[nf][1] = *(const bf16x8*)(d0 + 32768 + bBase + nf * 2048 + col1);
    }
    ST_A(1, T1);
    LGKM0;
    __builtin_amdgcn_s_setprio(1);
#pragma unroll
    for (int mf = 0; mf < 4; ++mf)
#pragma unroll
      for (int nf = 0; nf < 2; ++nf) {
        acc[mf][nf] = mfma16(aR[mf][0], b01[nf][0], acc[mf][nf]);
        acc[mf][nf] = mfma16(aR[mf][1], b01[nf][1], acc[mf][nf]);
      }
    __builtin_amdgcn_s_setprio(0);

    // ---- ph2: T0 mf0-3 x nf2-3 ----
    GATE10;
#pragma unroll
    for (int nf = 0; nf < 2; ++nf) {
      b23[nf][0] = *(const bf16x8*)(d0 + 32768 + 16384 + bBase + nf * 2048 + col0);
      b23[nf][1] = *(const bf16x8*)(d0 + 32768 + 16384 + bBase + nf * 2048 + col1);
    }
    ST_A(0, te);
    LGKM0;
    __builtin_amdgcn_s_setprio(1);
#pragma unroll
    for (int mf = 0; mf < 4; ++mf)
#pragma unroll
      for (int nf = 0; nf < 2; ++nf) {
        acc[mf][2 + nf] = mfma16(aR[mf][0], b23[nf][0], acc[mf][2 + nf]);
        acc[mf][2 + nf] = mfma16(aR[mf][1], b23[nf][1], acc[mf][2 + nf]);
      }
    __builtin_amdgcn_s_setprio(0);

    // ---- ph3: T0 mf4-7 x nf0-1 ----
    GATE10;
#pragma unroll
    for (int mf = 0; mf < 4; ++mf) {
      aR[mf][0] = *(const bf16x8*)(d0 + aBase + (4 + mf) * 2048 + col0);
      aR[mf][1] = *(const bf16x8*)(d0 + aBase + (4 + mf) * 2048 + col1);
    }
    ST_B(0, te);
    LGKM0;
    __builtin_amdgcn_s_setprio(1);
#pragma unroll
    for (int mf = 0; mf < 4; ++mf)
#pragma unroll
      for (int nf = 0; nf < 2; ++nf) {
        acc[4 + mf][nf] = mfma16(aR[mf][0], b01[nf][0], acc[4 + mf][nf]);
        acc[4 + mf][nf] = mfma16(aR[mf][1], b01[nf][1], acc[4 + mf][nf]);
      }
    __builtin_amdgcn_s_setprio(0);

    // ---- ph4: T0 mf4-7 x nf2-3 ----
    ST_B(1, te);
    __builtin_amdgcn_s_setprio(1);
#pragma unroll
    for (int mf = 0; mf < 4; ++mf)
#pragma unroll
      for (int nf = 0; nf < 2; ++nf) {
        acc[4 + mf][2 + nf] = mfma16(aR[mf][0], b23[nf][0], acc[4 + mf][2 + nf]);
        acc[4 + mf][2 + nf] = mfma16(aR[mf][1], b23[nf][1], acc[4 + mf][2 + nf]);
      }
    __builtin_amdgcn_s_setprio(0);

    // ---- ph5: T1 mf0-3 x nf0-1 ----
    GATE10;
#pragma unroll
    for (int mf = 0; mf < 4; ++mf) {
      aR[mf][0] = *(const bf16x8*)(d1 + aBase + mf * 2048 + col0);
      aR[mf][1] = *(const bf16x8*)(d1 + aBase + mf * 2048 + col1);
    }
#pragma unroll
    for (int nf = 0; nf < 2; ++nf) {
      b01[nf][0] = *(const bf16x8*)(d1 + 32768 + bBase + nf * 2048 + col0);
      b01[nf][1] = *(const bf16x8*)(d1 + 32768 + bBase + nf * 2048 + col1);
    }
    ST_A(1, te);
    LGKM0;
    __builtin_amdgcn_s_setprio(1);
#pragma unroll
    for (int mf = 0; mf < 4; ++mf)
#pragma unroll
      for (int nf = 0; nf < 2; ++nf) {
        acc[mf][nf] = mfma16(aR[mf][0], b01[nf][0], acc[mf][nf]);
        acc[mf][nf] = mfma16(aR[mf][1], b01[nf][1], acc[mf][nf]);
      }
    __builtin_amdgcn_s_setprio(0);

    // ---- ph6: T1 mf0-3 x nf2-3 ----
    GATE10;
#pragma unroll
    for (int nf = 0; nf < 2; ++nf) {
      b23[nf][0] = *(const bf16x8*)(d1 + 32768 + 16384 + bBase + nf * 2048 + col0);
      b23[nf][1] = *(const bf16x8*)(d1 + 32768 + 16384 + bBase + nf * 2048 + col1);
    }
    ST_A(0, to);
    LGKM0;
    __builtin_amdgcn_s_setprio(1);
#pragma unroll
    for (int mf = 0; mf < 4; ++mf)
#pragma unroll
      for (int nf = 0; nf < 2; ++nf) {
        acc[mf][2 + nf] = mfma16(aR[mf][0], b23[nf][0], acc[mf][2 + nf]);
        acc[mf][2 + nf] = mfma16(aR[mf][1], b23[nf][1], acc[mf][2 + nf]);
      }
    __builtin_amdgcn_s_setprio(0);

    // ---- ph7: T1 mf4-7 x nf0-1 ----
    GATE10;
#pragma unroll
    for (int mf = 0; mf < 4; ++mf) {
      aR[mf][0] = *(const bf16x8*)(d1 + aBase + (4 + mf) * 2048 + col0);
      aR[mf][1] = *(const bf16x8*)(d1 + aBase + (4 + mf) * 2048 + col1);
    }
    ST_B(0, to);
    LGKM0;
    __builtin_amdgcn_s_setprio(1);
#pragma unroll
    for (int mf = 0; mf < 4; ++mf)
#pragma unroll
      for (int nf = 0; nf < 2; ++nf) {
        acc[4 + mf][nf] = mfma16(aR[mf][0], b01[nf][0], acc[4 + mf][nf]);
        acc[4 + mf][nf] = mfma16(aR[mf][1], b01[nf][1], acc[4 + mf][nf]);
      }
    __builtin_amdgcn_s_setprio(0);

    // ---- ph8: T1 mf4-7 x nf2-3 ----
    ST_B(1, to);
    __builtin_amdgcn_s_setprio(1);
#pragma unroll
    for (int mf = 0; mf < 4; ++mf)
#pragma unroll
      for (int nf = 0; nf < 2; ++nf) {
        acc[4 + mf][2 + nf] = mfma16(aR[mf][0], b23[nf][0], acc[4 + mf][2 + nf]);
        acc[4 + mf][2 + nf] = mfma16(aR[mf][1], b23[nf][1], acc[4 + mf][2 + nf]);
      }
    __builtin_amdgcn_s_setprio(0);
  }
#undef ST_A
#undef ST_B
#undef GATE10
#undef LGKM0

  const float cscale = (bn < sbl) ? QSCALE : 1.0f;
#pragma unroll
  for (int mf = 0; mf < 8; ++mf)
#pragma unroll
    for (int nf = 0; nf < 4; ++nf)
#pragma unroll
      for (int r = 0; r < 4; ++r) {
        int rowc = bm * 256 + wr * 128 + mf * 16 + lg * 4 + r;
        int colc = bn * 256 + wc * 64 + nf * 16 + lr;
        float v = acc[mf][nf][r] * cscale;
        if constexpr (sizeof(OutT) == 2)
          C[(size_t)rowc * N + colc] = (OutT)f2b(v);
        else
          C[(size_t)rowc * N + colc] = v;
      }
}

// ---------------------------------------------------------------------------
// RoPE on K and V read from fused XQKV (row stride 6144; K col 4096+, V 5120+).
__global__ __launch_bounds__(256) void rope_kv(
    const unsigned short* __restrict__ XQKV,
    const float* __restrict__ fc, const float* __restrict__ fs,
    unsigned short* __restrict__ Kr, unsigned short* __restrict__ Vt) {
  __shared__ unsigned short Vl[128][66];
  const int t = threadIdx.x;
  const int bid = blockIdx.x;  // bkv*32 + stile
  const int stile = bid & 31, bkv = bid >> 5;
  const int b = bkv >> 3, kvh = bkv & 7;
  const int s0 = stile * 64;
  const int l = t & 63;
  const int jrow = t >> 6;

  for (int j = 0; j < 16; ++j) {
    int s = s0 + j * 4 + jrow;
    ushort2 v = *(const ushort2*)(XQKV + (size_t)(b * 2048 + s) * 6144 + 4096 +
                                  kvh * 128 + 2 * l);
    float c = fc[s * 64 + l], sn = fs[s * 64 + l];
    float xr = b2f(v.x), xi = b2f(v.y);
    ushort2 o;
    o.x = f2b(xr * c - xi * sn);
    o.y = f2b(xr * sn + xi * c);
    *(ushort2*)(Kr + ((size_t)bkv * 2048 + s) * 128 + 2 * l) = o;
  }
  for (int j = 0; j < 16; ++j) {
    int ss = j * 4 + jrow;
    int s = s0 + ss;
    ushort2 v = *(const ushort2*)(XQKV + (size_t)(b * 2048 + s) * 6144 + 5120 +
                                  kvh * 128 + 2 * l);
    float c = fc[s * 64 + l], sn = fs[s * 64 + l];
    float xr = b2f(v.x), xi = b2f(v.y);
    Vl[2 * l][ss] = f2b(xr * c - xi * sn);
    Vl[2 * l + 1][ss] = f2b(xr * sn + xi * c);
  }
  __syncthreads();
  const int d = t >> 1, half = t & 1;
  unsigned short* vdst = Vt + ((size_t)bkv * 128 + d) * 2048 + s0 + half * 32;
#pragma unroll
  for (int e = 0; e < 32; e += 4) {
    ushort4 pk;
    pk.x = Vl[d][half * 32 + e];
    pk.y = Vl[d][half * 32 + e + 1];
    pk.z = Vl[d][half * 32 + e + 2];
    pk.w = Vl[d][half * 32 + e + 3];
    *(ushort4*)(vdst + e) = pk;
  }
}

// ---------------------------------------------------------------------------
// Flash attention (round-10/11 kernel, unchanged). Grid 512; 4 waves x 64 q.
__global__ __launch_bounds__(256, 2) void attn_fwd(
    const unsigned short* __restrict__ XQ, const unsigned short* __restrict__ Kr,
    const unsigned short* __restrict__ Vt, unsigned short* __restrict__ AO) {
  extern __shared__ char smem[];  // 49152
  char* Ksm = smem;                                      // [2][8192]
  char* Vsm = smem + 16384;                              // [2][8192]
  unsigned short* Ps = (unsigned short*)(smem + 32768);  // [4][4][64][8]
  const int t = threadIdx.x;
  const int lane = t & 63, w = t >> 6;
  const int lr = lane & 15, lg = lane >> 4;

  const int bid = blockIdx.x;
  const int nwg = gridDim.x;  // 512
  const int swz = (bid & 7) * (nwg >> 3) + (bid >> 3);
  const int qt = swz & 7;
  const int bh = swz >> 3;
  const int b = bh >> 5, h = bh & 31;
  const int bkv = b * 8 + (h >> 2);

  bf16x8 qf[4][4];
#pragma unroll
  for (int q4 = 0; q4 < 4; ++q4) {
    const unsigned short* qp =
        XQ + ((size_t)(b * 2048 + qt * 256 + w * 64 + q4 * 16 + lr)) * 6144 +
        h * 128 + lg * 8;
#pragma unroll
    for (int dc = 0; dc < 4; ++dc) qf[q4][dc] = *(const bf16x8*)(qp + dc * 32);
  }

  f32x4 acc[4][8];
#pragma unroll
  for (int q4 = 0; q4 < 4; ++q4)
#pragma unroll
    for (int i = 0; i < 8; ++i) acc[q4][i] = (f32x4){0.f, 0.f, 0.f, 0.f};
  float l_[4][4];
#pragma unroll
  for (int q4 = 0; q4 < 4; ++q4)
#pragma unroll
    for (int r = 0; r < 4; ++r) l_[q4][r] = 0.f;

  const unsigned short* Kbase = Kr + (size_t)bkv * 2048 * 128;
  const unsigned short* Vbase = Vt + (size_t)bkv * 128 * 2048;

  const int c0 = t, c1 = t + 256;
  const int kK0 = c0 & 31, dC0 = c0 >> 5;
  const int kK1 = c1 & 31, dC1 = c1 >> 5;
  const int vD0 = c0 & 127, vKc0 = c0 >> 7;
  const int vD1 = c1 & 127, vKc1 = c1 >> 7;
  const int dstb0 = (c0 & ~63) * 16;
  const int dstb1 = (c1 & ~63) * 16;

#define STAGE_KV(bufi, kt)                                                     \
  {                                                                            \
    char* kd = Ksm + (bufi)*8192;                                              \
    char* vd = Vsm + (bufi)*8192;                                              \
    load16(Kbase + (size_t)((kt)*32 + kK0) * 128 + dC0 * 8, kd + dstb0);       \
    load16(Kbase + (size_t)((kt)*32 + kK1) * 128 + dC1 * 8, kd + dstb1);       \
    load16(Vbase + (size_t)vD0 * 2048 + (kt)*32 + vKc0 * 8, vd + dstb0);       \
    load16(Vbase + (size_t)vD1 * 2048 + (kt)*32 + vKc1 * 8, vd + dstb1);       \
  }

  STAGE_KV(0, 0);
  asm volatile("s_waitcnt vmcnt(0)" ::: "memory");
  __builtin_amdgcn_s_barrier();

  unsigned short* Pw = Ps + w * 2048;              // [4 kc][64 q][8]
  const int pbase = (lr >> 3) * 512 + (lr & 7);    // halfword offset

  for (int kt = 0; kt < 64; ++kt) {
    const int cur = kt & 1;
    if (kt < 63) STAGE_KV(cur ^ 1, kt + 1);

    const char* Kc = Ksm + cur * 8192;
    const char* Vc = Vsm + cur * 8192;

#pragma unroll
    for (int nf = 0; nf < 2; ++nf) {
      f32x4 s[4];
#pragma unroll
      for (int q4 = 0; q4 < 4; ++q4) s[q4] = (f32x4){0.f, 0.f, 0.f, 0.f};
#pragma unroll
      for (int dc = 0; dc < 4; ++dc) {
        bf16x8 kf =
            *(const bf16x8*)(Kc + ((dc * 4 + lg) * 32 + nf * 16 + lr) * 16);
#pragma unroll
        for (int q4 = 0; q4 < 4; ++q4) s[q4] = mfma16(qf[q4][dc], kf, s[q4]);
      }
      const int pb = pbase + nf * 1024;  // kc = nf*2 + (lr>>3)
#pragma unroll
      for (int q4 = 0; q4 < 4; ++q4)
#pragma unroll
        for (int r = 0; r < 4; ++r) {
          float p = __builtin_amdgcn_exp2f(s[q4][r]);
          l_[q4][r] += p;
          Pw[pb + (q4 * 16 + lg * 4 + r) * 8] = f2b_fast(p);
        }
    }

    bf16x8 pf[4];
#pragma unroll
    for (int q4 = 0; q4 < 4; ++q4)
      pf[q4] = *(const bf16x8*)(Pw + lg * 512 + (q4 * 16 + lr) * 8);
#pragma unroll
    for (int dt = 0; dt < 8; ++dt) {
      bf16x8 vf = *(const bf16x8*)(Vc + (lg * 128 + dt * 16 + lr) * 16);
#pragma unroll
      for (int q4 = 0; q4 < 4; ++q4)
        acc[q4][dt] = mfma16(pf[q4], vf, acc[q4][dt]);
    }

    asm volatile("s_waitcnt vmcnt(0)" ::: "memory");
    __builtin_amdgcn_s_barrier();
  }
#undef STAGE_KV

#pragma unroll
  for (int q4 = 0; q4 < 4; ++q4)
#pragma unroll
    for (int r = 0; r < 4; ++r) {
#pragma unroll
      for (int o = 1; o < 16; o <<= 1) l_[q4][r] += __shfl_xor(l_[q4][r], o);
    }

#pragma unroll
  for (int q4 = 0; q4 < 4; ++q4)
#pragma unroll
    for (int r = 0; r < 4; ++r) {
      float inv = 1.f / l_[q4][r];
      size_t rowb =
          ((size_t)(b * 2048 + qt * 256 + w * 64 + q4 * 16 + lg * 4 + r)) * 4096 +
          h * 128;
#pragma unroll
      for (int dt = 0; dt < 8; ++dt)
        AO[rowb + dt * 16 + lr] = f2b_fast(acc[q4][dt][r] * inv);
    }
}

// ---------------------------------------------------------------------------
extern "C" void kernel_launch(void* const* d_in, const int* in_sizes, int n_in,
                              void* d_out, int out_size, void* d_ws, size_t ws_size,
                              hipStream_t stream) {
  const float* x  = (const float*)d_in[0];
  const float* fc = (const float*)d_in[2];
  const float* fs = (const float*)d_in[3];
  const float* wq = (const float*)d_in[4];
  const float* wk = (const float*)d_in[5];
  const float* wv = (const float*)d_in[6];
  const float* wo = (const float*)d_in[7];

  const size_t MB = 1024ull * 1024ull;
  char* ws = (char*)d_ws;
  unsigned short* Xb   = (unsigned short*)(ws);           // 32MB, dead after QKV gemm
  unsigned short* Wsc  = (unsigned short*)(ws + 32 * MB); // 48MB (wq|wk|wv), later wo
  unsigned short* Kr   = (unsigned short*)(ws);           // [0,8) reuse Xb
  unsigned short* Vt   = (unsigned short*)(ws + 8 * MB);  // [8,16)
  unsigned short* AO   = (unsigned short*)(ws + 80 * MB); // 32MB
  unsigned short* XQKV = (unsigned short*)d_out;          // 48MB of 64MB d_out

  (void)hipFuncSetAttribute((const void*)gemm256<unsigned short>,
                            hipFuncAttributeMaxDynamicSharedMemorySize, 131072);
  (void)hipFuncSetAttribute((const void*)gemm256<float>,
                            hipFuncAttributeMaxDynamicSharedMemorySize, 131072);
  (void)hipFuncSetAttribute((const void*)attn_fwd,
                            hipFuncAttributeMaxDynamicSharedMemorySize, 49152);

  dim3 blk(256);
  dim3 blk512(512);
  cvt_f32_bf16<<<2048, blk, 0, stream>>>(x, Xb, (2 * 2048 * 4096) / 4);
  cvt_w3<<<2048, blk, 0, stream>>>(wq, wk, wv, Wsc);
  gemm256<unsigned short><<<384, blk512, 131072, stream>>>(
      Xb, Wsc, XQKV, 4096, 6144, 4096, /*sbl=*/16);
  rope_kv<<<512, blk, 0, stream>>>(XQKV, fc, fs, Kr, Vt);
  attn_fwd<<<512, blk, 49152, stream>>>(XQKV, Kr, Vt, AO);
  cvt_f32_bf16<<<2048, blk, 0, stream>>>(wo, Wsc, (4096 * 4096) / 4);
  gemm256<float><<<256, blk512, 131072, stream>>>(
      AO, Wsc, (float*)d_out, 4096, 4096, 4096, /*sbl=*/0);
}

// Round 14
// 539.976 us; speedup vs baseline: 1.2491x; 1.0047x over previous
//
#include <hip/hip_runtime.h>
#include <hip/hip_bf16.h>

// ---------------------------------------------------------------------------
// SelfAttention (B=2,S=2048,D=4096, NH=32,NKV=8,HD=128, NREP=4, non-causal)
// RoPE on K and V (reference quirk), NOT on Q.
// Round 14: QKV projection -> gemm128 (128x256 tile, grid 768 = 3 FULL
//   rounds on 256 CUs, no tail). r11 phase skeleton: 4 phases/iter x 16
//   MFMA, counted vmcnt(4) gates at ph1/ph3, stage stream
//   B1(T1) | A,B0(te) | B1(te) | A,B0(to), barrier每phase (WAR-checked).
//   O-projection keeps the r11 BK=64 8-phase gemm256 (grid 256, no tail).
// ---------------------------------------------------------------------------

typedef short bf16x8 __attribute__((ext_vector_type(8)));
typedef float f32x4 __attribute__((ext_vector_type(4)));

__device__ __forceinline__ void load16(const void* g, void* l) {
  __builtin_amdgcn_global_load_lds(
      (const __attribute__((address_space(1))) void*)g,
      (__attribute__((address_space(3))) void*)l, 16, 0, 0);
}

__device__ __forceinline__ f32x4 mfma16(bf16x8 a, bf16x8 b, f32x4 c) {
  return __builtin_amdgcn_mfma_f32_16x16x32_bf16(a, b, c, 0, 0, 0);
}

__device__ __forceinline__ unsigned short f2b(float f) {
  union { float f; unsigned int u; } v; v.f = f;
  unsigned int u = v.u;
  return (unsigned short)((u + 0x7fffu + ((u >> 16) & 1u)) >> 16);
}
__device__ __forceinline__ float b2f(unsigned short u) {
  union { unsigned int u; float f; } v; v.u = ((unsigned int)u) << 16;
  return v.f;
}
__device__ __forceinline__ unsigned short f2b_fast(float f) {
  __hip_bfloat16 h = __float2bfloat16(f);
  return *reinterpret_cast<unsigned short*>(&h);
}

#define QSCALE (0.08838834764831845f * 1.4426950408889634f)

// ---------------------------------------------------------------------------
__global__ __launch_bounds__(256) void cvt_f32_bf16(
    const float* __restrict__ in, unsigned short* __restrict__ out, int n4) {
  int idx = blockIdx.x * 256 + threadIdx.x;
  int stride = gridDim.x * 256;
  for (int i = idx; i < n4; i += stride) {
    float4 v = reinterpret_cast<const float4*>(in)[i];
    ushort4 o;
    o.x = f2b(v.x); o.y = f2b(v.y); o.z = f2b(v.z); o.w = f2b(v.w);
    reinterpret_cast<ushort4*>(out)[i] = o;
  }
}

// merged wq|wk|wv conversion into contiguous Wsc
__global__ __launch_bounds__(256) void cvt_w3(
    const float* __restrict__ wq, const float* __restrict__ wk,
    const float* __restrict__ wv, unsigned short* __restrict__ out) {
  const int nq = 4096 * 4096 / 4, nk = 1024 * 4096 / 4;
  const int tot = nq + 2 * nk;
  int idx = blockIdx.x * 256 + threadIdx.x;
  int stride = gridDim.x * 256;
  for (int i = idx; i < tot; i += stride) {
    int j = i;
    const float4* src;
    if (j < nq) {
      src = reinterpret_cast<const float4*>(wq);
    } else if (j < nq + nk) {
      src = reinterpret_cast<const float4*>(wk); j -= nq;
    } else {
      src = reinterpret_cast<const float4*>(wv); j -= nq + nk;
    }
    float4 v = src[j];
    ushort4 o;
    o.x = f2b(v.x); o.y = f2b(v.y); o.z = f2b(v.z); o.w = f2b(v.w);
    reinterpret_cast<ushort4*>(out)[i] = o;
  }
}

// ---------------------------------------------------------------------------
// gemm128: 128x256 tile, BK=64, 8 waves (2Mx4N), per-wave 64x64.
// LDS: dbuf d = smem + (tile&1)*49152; A [128 rows][64 hw] @ +0 (16KB),
// B [256 prow][64 hw] @ +16384 (32KB). Rows 128B, k-slot XOR by (row&7);
// B rows permuted prow = (nf>>1)*128 + wc*32 + (nf&1)*16 + lr (r11 format).
// 4 phases/iter (tiles T0=2i dbuf0, T1=2i+1 dbuf1), 16 MFMA each:
//   ph1 GATE vmcnt(4): read A(T0)x8 + b01(T0)x4 ; ST_B1(T1) ; MFMA nf01
//   ph2 barrier:       read b23(T0)x4 ; ST_A(te), ST_B0(te) ; MFMA nf23
//   ph3 GATE vmcnt(4): read A(T1)x8 + b01(T1)x4 ; ST_B1(te) ; MFMA nf01
//   ph4 barrier:       read b23(T1)x4 ; ST_A(to), ST_B0(to) ; MFMA nf23
// Ledger: every stage >=1 barrier after its region's last read; gates force
// exactly the needed halves (prologue A0,B0_0,B1_0,A1,B0_1 matches stream).
template <typename OutT>
__global__ __launch_bounds__(512, 1) void gemm128(
    const unsigned short* __restrict__ A, const unsigned short* __restrict__ Bw,
    OutT* __restrict__ C, int M, int N, int K, int sbl) {
  extern __shared__ char smem[];  // 98304
  const int tid = threadIdx.x;
  const int lane = tid & 63;
  const int w = tid >> 6;
  const int lr = lane & 15, lg = lane >> 4;
  const int wr = w >> 2, wc = w & 3;

  const int nbn = N >> 8;
  const int bid = blockIdx.x, nwg = gridDim.x;
  const int swz = (bid & 7) * (nwg >> 3) + (bid >> 3);  // nwg % 8 == 0
  const int bm = swz / nbn, bn = swz % nbn;

  const unsigned short* Ag = A + (size_t)bm * 128 * K;
  const unsigned short* Bg = Bw + (size_t)bn * 256 * K;

  // A staging: 1024 chunks (16KB), 2/thread. row = c>>3 (0..127).
  int aoffs[2], sdA[2];
#pragma unroll
  for (int j = 0; j < 2; ++j) {
    const int c = tid + j * 512;
    const int row = c >> 3;
    aoffs[j] = row * K + (((c & 7) ^ (row & 7)) << 3);
    sdA[j] = ((tid & ~63) << 4) + j * 8192;
  }
  // B staging: 2048 chunks (32KB), 4/thread, inverse-permuted rows (r11).
  int boffs[4], sdB[4];
#pragma unroll
  for (int j = 0; j < 4; ++j) {
    const int c = tid + j * 512;
    const int u = c >> 3;
    const int br = ((u & 127) >> 5) * 64 + (u >> 7) * 32 + (u & 31);
    boffs[j] = br * K + (((c & 7) ^ (u & 7)) << 3);
    sdB[j] = ((tid & ~63) << 4) + j * 8192;
  }

#define ST_A(tt)                                                              \
  {                                                                           \
    char* d = smem + (((tt)&1) * 49152);                                      \
    load16(Ag + aoffs[0] + ((tt) << 6), d + sdA[0]);                          \
    load16(Ag + aoffs[1] + ((tt) << 6), d + sdA[1]);                          \
  }
#define ST_B(hh, tt)                                                          \
  {                                                                           \
    char* d = smem + (((tt)&1) * 49152) + 16384;                              \
    load16(Bg + boffs[(hh)*2] + ((tt) << 6), d + sdB[(hh)*2]);                \
    load16(Bg + boffs[(hh)*2 + 1] + ((tt) << 6), d + sdB[(hh)*2 + 1]);        \
  }
#define GATE4                                                                 \
  asm volatile("s_waitcnt vmcnt(4)" ::: "memory");                            \
  __builtin_amdgcn_s_barrier();
#define BAR __builtin_amdgcn_s_barrier()
#define LGKM0                                                                 \
  asm volatile("s_waitcnt lgkmcnt(0)" ::: "memory");                          \
  __builtin_amdgcn_sched_barrier(0);

  f32x4 acc[4][4];
#pragma unroll
  for (int m = 0; m < 4; ++m)
#pragma unroll
    for (int n = 0; n < 4; ++n) acc[m][n] = (f32x4){0.f, 0.f, 0.f, 0.f};

  // prologue (stream order): A(0),B0(0),B1(0),A(1),B0(1)  [10 loads]
  ST_A(0); ST_B(0, 0); ST_B(1, 0); ST_A(1); ST_B(0, 1);

  const int NT = K >> 6;   // 64
  const int NI = NT >> 1;  // 32
  const int xr = (lr & 7) << 4;
  const int aBase = (wr * 64 + lr) * 128;   // + mf*2048 + col
  const int bBase = (wc * 32 + lr) * 128;   // + (nf&1)*2048 (+16384 if nf>=2)
  const int col0 = (lg * 16) ^ xr;
  const int col1 = (64 + lg * 16) ^ xr;

  bf16x8 aR[4][2], b01[2][2], b23[2][2];

  for (int i = 0; i < NI; ++i) {
    const int T1 = 2 * i + 1;
    const int te = (2 * i + 2 < NT) ? 2 * i + 2 : 0;  // wrap keeps stream uniform
    const int to = (2 * i + 3 < NT) ? 2 * i + 3 : 1;
    const char* d0 = smem;            // dbuf0 (even tile)
    const char* d1 = smem + 49152;    // dbuf1 (odd tile)

    // ---- ph1: T0, nf0-1 ----
    GATE4;
#pragma unroll
    for (int mf = 0; mf < 4; ++mf) {
      aR[mf][0] = *(const bf16x8*)(d0 + aBase + mf * 2048 + col0);
      aR[mf][1] = *(const bf16x8*)(d0 + aBase + mf * 2048 + col1);
    }
#pragma unroll
    for (int nf = 0; nf < 2; ++nf) {
      b01[nf][0] = *(const bf16x8*)(d0 + 16384 + bBase + nf * 2048 + col0);
      b01[nf][1] = *(const bf16x8*)(d0 + 16384 + bBase + nf * 2048 + col1);
    }
    ST_B(1, T1);
    LGKM0;
    __builtin_amdgcn_s_setprio(1);
#pragma unroll
    for (int mf = 0; mf < 4; ++mf)
#pragma unroll
      for (int nf = 0; nf < 2; ++nf) {
        acc[mf][nf] = mfma16(aR[mf][0], b01[nf][0], acc[mf][nf]);
        acc[mf][nf] = mfma16(aR[mf][1], b01[nf][1], acc[mf][nf]);
      }
    __builtin_amdgcn_s_setprio(0);

    // ---- ph2: T0, nf2-3 ----
    BAR;
#pragma unroll
    for (int nf = 0; nf < 2; ++nf) {
      b23[nf][0] = *(const bf16x8*)(d0 + 16384 + 16384 + bBase + nf * 2048 + col0);
      b23[nf][1] = *(const bf16x8*)(d0 + 16384 + 16384 + bBase + nf * 2048 + col1);
    }
    ST_A(te);
    ST_B(0, te);
    LGKM0;
    __builtin_amdgcn_s_setprio(1);
#pragma unroll
    for (int mf = 0; mf < 4; ++mf)
#pragma unroll
      for (int nf = 0; nf < 2; ++nf) {
        acc[mf][2 + nf] = mfma16(aR[mf][0], b23[nf][0], acc[mf][2 + nf]);
        acc[mf][2 + nf] = mfma16(aR[mf][1], b23[nf][1], acc[mf][2 + nf]);
      }
    __builtin_amdgcn_s_setprio(0);

    // ---- ph3: T1, nf0-1 ----
    GATE4;
#pragma unroll
    for (int mf = 0; mf < 4; ++mf) {
      aR[mf][0] = *(const bf16x8*)(d1 + aBase + mf * 2048 + col0);
      aR[mf][1] = *(const bf16x8*)(d1 + aBase + mf * 2048 + col1);
    }
#pragma unroll
    for (int nf = 0; nf < 2; ++nf) {
      b01[nf][0] = *(const bf16x8*)(d1 + 16384 + bBase + nf * 2048 + col0);
      b01[nf][1] = *(const bf16x8*)(d1 + 16384 + bBase + nf * 2048 + col1);
    }
    ST_B(1, te);
    LGKM0;
    __builtin_amdgcn_s_setprio(1);
#pragma unroll
    for (int mf = 0; mf < 4; ++mf)
#pragma unroll
      for (int nf = 0; nf < 2; ++nf) {
        acc[mf][nf] = mfma16(aR[mf][0], b01[nf][0], acc[mf][nf]);
        acc[mf][nf] = mfma16(aR[mf][1], b01[nf][1], acc[mf][nf]);
      }
    __builtin_amdgcn_s_setprio(0);

    // ---- ph4: T1, nf2-3 ----
    BAR;
#pragma unroll
    for (int nf = 0; nf < 2; ++nf) {
      b23[nf][0] = *(const bf16x8*)(d1 + 16384 + 16384 + bBase + nf * 2048 + col0);
      b23[nf][1] = *(const bf16x8*)(d1 + 16384 + 16384 + bBase + nf * 2048 + col1);
    }
    ST_A(to);
    ST_B(0, to);
    LGKM0;
    __builtin_amdgcn_s_setprio(1);
#pragma unroll
    for (int mf = 0; mf < 4; ++mf)
#pragma unroll
      for (int nf = 0; nf < 2; ++nf) {
        acc[mf][2 + nf] = mfma16(aR[mf][0], b23[nf][0], acc[mf][2 + nf]);
        acc[mf][2 + nf] = mfma16(aR[mf][1], b23[nf][1], acc[mf][2 + nf]);
      }
    __builtin_amdgcn_s_setprio(0);
  }
#undef ST_A
#undef ST_B
#undef GATE4
#undef BAR
#undef LGKM0

  const float cscale = (bn < sbl) ? QSCALE : 1.0f;
#pragma unroll
  for (int mf = 0; mf < 4; ++mf)
#pragma unroll
    for (int nf = 0; nf < 4; ++nf)
#pragma unroll
      for (int r = 0; r < 4; ++r) {
        int rowc = bm * 128 + wr * 64 + mf * 16 + lg * 4 + r;
        int colc = bn * 256 + wc * 64 + nf * 16 + lr;
        float v = acc[mf][nf][r] * cscale;
        if constexpr (sizeof(OutT) == 2)
          C[(size_t)rowc * N + colc] = (OutT)f2b(v);
        else
          C[(size_t)rowc * N + colc] = v;
      }
}

// ---------------------------------------------------------------------------
// Round-11 gemm256 (verbatim) — O projection (grid 256, zero tail).
template <typename OutT>
__global__ __launch_bounds__(512, 2) void gemm256(
    const unsigned short* __restrict__ A, const unsigned short* __restrict__ Bw,
    OutT* __restrict__ C, int M, int N, int K, int sbl) {
  extern __shared__ char smem[];  // 131072
  const int tid = threadIdx.x;
  const int lane = tid & 63;
  const int w = tid >> 6;
  const int lr = lane & 15, lg = lane >> 4;
  const int wr = w >> 2, wc = w & 3;

  const int nbn = N >> 8;
  const int bid = blockIdx.x, nwg = gridDim.x;
  const int swz = (bid & 7) * (nwg >> 3) + (bid >> 3);
  const int bm = swz / nbn, bn = swz % nbn;

  const unsigned short* Ag = A + (size_t)bm * 256 * K;
  const unsigned short* Bg = Bw + (size_t)bn * 256 * K;

  int aoffs[4], boffs[4], sdst[4];
#pragma unroll
  for (int j = 0; j < 4; ++j) {
    const int c = tid + j * 512;
    const int u = c >> 3;
    const int slot = ((c & 7) ^ (u & 7)) << 3;
    aoffs[j] = u * K + slot;
    const int br = ((u & 127) >> 5) * 64 + (u >> 7) * 32 + (u & 31);
    boffs[j] = br * K + slot;
    sdst[j] = ((tid & ~63) << 4) + j * 8192;
  }

#define ST_A(hh, tt)                                                          \
  {                                                                           \
    char* d = smem + (((tt)&1) * 65536);                                      \
    load16(Ag + aoffs[(hh)] + ((tt) << 6), d + sdst[(hh)]);                   \
    load16(Ag + aoffs[(hh) + 2] + ((tt) << 6), d + sdst[(hh) + 2]);           \
  }
#define ST_B(hh, tt)                                                          \
  {                                                                           \
    char* d = smem + (((tt)&1) * 65536) + 32768;                              \
    load16(Bg + boffs[(hh)*2] + ((tt) << 6), d + sdst[(hh)*2]);               \
    load16(Bg + boffs[(hh)*2 + 1] + ((tt) << 6), d + sdst[(hh)*2 + 1]);       \
  }
#define GATE10                                                                \
  asm volatile("s_waitcnt vmcnt(10)" ::: "memory");                           \
  __builtin_amdgcn_s_barrier();
#define LGKM0                                                                 \
  asm volatile("s_waitcnt lgkmcnt(0)" ::: "memory");                          \
  __builtin_amdgcn_sched_barrier(0);

  f32x4 acc[8][4];
#pragma unroll
  for (int m = 0; m < 8; ++m)
#pragma unroll
    for (int n = 0; n < 4; ++n) acc[m][n] = (f32x4){0.f, 0.f, 0.f, 0.f};

  ST_A(0, 0); ST_B(0, 0); ST_B(1, 0); ST_A(1, 0);
  ST_A(0, 1); ST_B(0, 1); ST_B(1, 1);

  const int NT = K >> 6;
  const int NI = NT >> 1;
  const int xr = (lr & 7) << 4;
  const int aBase = (wr * 128 + lr) * 128;
  const int bBase = (wc * 32 + lr) * 128;
  const int col0 = (lg * 16) ^ xr;
  const int col1 = (64 + lg * 16) ^ xr;

  bf16x8 aR[4][2], b01[2][2], b23[2][2];

  for (int i = 0; i < NI; ++i) {
    const int T1 = 2 * i + 1;
    const int te = (2 * i + 2 < NT) ? 2 * i + 2 : 0;
    const int to = (2 * i + 3 < NT) ? 2 * i + 3 : 1;
    const char* d0 = smem;
    const char* d1 = smem + 65536;

    GATE10;
#pragma unroll
    for (int mf = 0; mf < 4; ++mf) {
      aR[mf][0] = *(const bf16x8*)(d0 + aBase + mf * 2048 + col0);
      aR[mf][1] = *(const bf16x8*)(d0 + aBase + mf * 2048 + col1);
    }
#pragma unroll
    for (int nf = 0; nf < 2; ++nf) {
      b01[nf][0] = *(const bf16x8*)(d0 + 32768 + bBase + nf * 2048 + col0);
      b01[nf][1] = *(const bf16x8*)(d0 + 32768 + bBase + nf * 2048 + col1);
    }
    ST_A(1, T1);
    LGKM0;
    __builtin_amdgcn_s_setprio(1);
#pragma unroll
    for (int mf = 0; mf < 4; ++mf)
#pragma unroll
      for (int nf = 0; nf < 2; ++nf) {
        acc[mf][nf] = mfma16(aR[mf][0], b01[nf][0], acc[mf][nf]);
        acc[mf][nf] = mfma16(aR[mf][1], b01[nf][1], acc[mf][nf]);
      }
    __builtin_amdgcn_s_setprio(0);

    GATE10;
#pragma unroll
    for (int nf = 0; nf < 2; ++nf) {
      b23[nf][0] = *(const bf16x8*)(d0 + 32768 + 16384 + bBase + nf * 2048 + col0);
      b23[nf][1] = *(const bf16x8*)(d0 + 32768 + 16384 + bBase + nf * 2048 + col1);
    }
    ST_A(0, te);
    LGKM0;
    __builtin_amdgcn_s_setprio(1);
#pragma unroll
    for (int mf = 0; mf < 4; ++mf)
#pragma unroll
      for (int nf = 0; nf < 2; ++nf) {
        acc[mf][2 + nf] = mfma16(aR[mf][0], b23[nf][0], acc[mf][2 + nf]);
        acc[mf][2 + nf] = mfma16(aR[mf][1], b23[nf][1], acc[mf][2 + nf]);
      }
    __builtin_amdgcn_s_setprio(0);

    GATE10;
#pragma unroll
    for (int mf = 0; mf < 4; ++mf) {
      aR[mf][0] = *(const bf16x8*)(d0 + aBase + (4 + mf) * 2048 + col0);
      aR[mf][1] = *(const bf16x8*)(d0 + aBase + (4 + mf) * 2048 + col1);
    }
    ST_B(0, te);
    LGKM0;
    __builtin_amdgcn_s_setprio(1);
#pragma unroll
    for (int mf = 0; mf < 4; ++mf)
#pragma unroll
      for (int nf = 0; nf < 2; ++nf) {
        acc[4 + mf][nf] = mfma16(aR[mf][0], b01[nf][0], acc[4 + mf][nf]);
        acc[4 + mf][nf] = mfma16(aR[mf][1], b01[nf][1], acc[4 + mf][nf]);
      }
    __builtin_amdgcn_s_setprio(0);

    ST_B(1, te);
    __builtin_amdgcn_s_setprio(1);
#pragma unroll
    for (int mf = 0; mf < 4; ++mf)
#pragma unroll
      for (int nf = 0; nf < 2; ++nf) {
        acc[4 + mf][2 + nf] = mfma16(aR[mf][0], b23[nf][0], acc[4 + mf][2 + nf]);
        acc[4 + mf][2 + nf] = mfma16(aR[mf][1], b23[nf][1], acc[4 + mf][2 + nf]);
      }
    __builtin_amdgcn_s_setprio(0);

    GATE10;
#pragma unroll
    for (int mf = 0; mf < 4; ++mf) {
      aR[mf][0] = *(const bf16x8*)(d1 + aBase + mf * 2048 + col0);
      aR[mf][1] = *(const bf16x8*)(d1 + aBase + mf * 2048 + col1);
    }
#pragma unroll
    for (int nf = 0; nf < 2; ++nf) {
      b01[nf][0] = *(const bf16x8*)(d1 + 32768 + bBase + nf * 2048 + col0);
      b01[nf][1] = *(const bf16x8*)(d1 + 32768 + bBase + nf * 2048 + col1);
    }
    ST_A(1, te);
    LGKM0;
    __builtin_amdgcn_s_setprio(1);
#pragma unroll
    for (int mf = 0; mf < 4; ++mf)
#pragma unroll
      for (int nf = 0; nf < 2; ++nf) {
        acc[mf][nf] = mfma16(aR[mf][0], b01[nf][0], acc[mf][nf]);
        acc[mf][nf] = mfma16(aR[mf][1], b01[nf][1], acc[mf][nf]);
      }
    __builtin_amdgcn_s_setprio(0);

    GATE10;
#pragma unroll
    for (int nf = 0; nf < 2; ++nf) {
      b23[nf][0] = *(const bf16x8*)(d1 + 32768 + 16384 + bBase + nf * 2048 + col0);
      b23[nf][1] = *(const bf16x8*)(d1 + 32768 + 16384 + bBase + nf * 2048 + col1);
    }
    ST_A(0, to);
    LGKM0;
    __builtin_amdgcn_s_setprio(1);
#pragma unroll
    for (int mf = 0; mf < 4; ++mf)
#pragma unroll
      for (int nf = 0; nf < 2; ++nf) {
        acc[mf][2 + nf] = mfma16(aR[mf][0], b23[nf][0], acc[mf][2 + nf]);
        acc[mf][2 + nf] = mfma16(aR[mf][1], b23[nf][1], acc[mf][2 + nf]);
      }
    __builtin_amdgcn_s_setprio(0);

    GATE10;
#pragma unroll
    for (int mf = 0; mf < 4; ++mf) {
      aR[mf][0] = *(const bf16x8*)(d1 + aBase + (4 + mf) * 2048 + col0);
      aR[mf][1] = *(const bf16x8*)(d1 + aBase + (4 + mf) * 2048 + col1);
    }
    ST_B(0, to);
    LGKM0;
    __builtin_amdgcn_s_setprio(1);
#pragma unroll
    for (int mf = 0; mf < 4; ++mf)
#pragma unroll
      for (int nf = 0; nf < 2; ++nf) {
        acc[4 + mf][nf] = mfma16(aR[mf][0], b01[nf][0], acc[4 + mf][nf]);
        acc[4 + mf][nf] = mfma16(aR[mf][1], b01[nf][1], acc[4 + mf][nf]);
      }
    __builtin_amdgcn_s_setprio(0);

    ST_B(1, to);
    __builtin_amdgcn_s_setprio(1);
#pragma unroll
    for (int mf = 0; mf < 4; ++mf)
#pragma unroll
      for (int nf = 0; nf < 2; ++nf) {
        acc[4 + mf][2 + nf] = mfma16(aR[mf][0], b23[nf][0], acc[4 + mf][2 + nf]);
        acc[4 + mf][2 + nf] = mfma16(aR[mf][1], b23[nf][1], acc[4 + mf][2 + nf]);
      }
    __builtin_amdgcn_s_setprio(0);
  }
#undef ST_A
#undef ST_B
#undef GATE10
#undef LGKM0

  const float cscale = (bn < sbl) ? QSCALE : 1.0f;
#pragma unroll
  for (int mf = 0; mf < 8; ++mf)
#pragma unroll
    for (int nf = 0; nf < 4; ++nf)
#pragma unroll
      for (int r = 0; r < 4; ++r) {
        int rowc = bm * 256 + wr * 128 + mf * 16 + lg * 4 + r;
        int colc = bn * 256 + wc * 64 + nf * 16 + lr;
        float v = acc[mf][nf][r] * cscale;
        if constexpr (sizeof(OutT) == 2)
          C[(size_t)rowc * N + colc] = (OutT)f2b(v);
        else
          C[(size_t)rowc * N + colc] = v;
      }
}

// ---------------------------------------------------------------------------
// RoPE on K and V read from fused XQKV (row stride 6144; K col 4096+, V 5120+).
__global__ __launch_bounds__(256) void rope_kv(
    const unsigned short* __restrict__ XQKV,
    const float* __restrict__ fc, const float* __restrict__ fs,
    unsigned short* __restrict__ Kr, unsigned short* __restrict__ Vt) {
  __shared__ unsigned short Vl[128][66];
  const int t = threadIdx.x;
  const int bid = blockIdx.x;  // bkv*32 + stile
  const int stile = bid & 31, bkv = bid >> 5;
  const int b = bkv >> 3, kvh = bkv & 7;
  const int s0 = stile * 64;
  const int l = t & 63;
  const int jrow = t >> 6;

  for (int j = 0; j < 16; ++j) {
    int s = s0 + j * 4 + jrow;
    ushort2 v = *(const ushort2*)(XQKV + (size_t)(b * 2048 + s) * 6144 + 4096 +
                                  kvh * 128 + 2 * l);
    float c = fc[s * 64 + l], sn = fs[s * 64 + l];
    float xr = b2f(v.x), xi = b2f(v.y);
    ushort2 o;
    o.x = f2b(xr * c - xi * sn);
    o.y = f2b(xr * sn + xi * c);
    *(ushort2*)(Kr + ((size_t)bkv * 2048 + s) * 128 + 2 * l) = o;
  }
  for (int j = 0; j < 16; ++j) {
    int ss = j * 4 + jrow;
    int s = s0 + ss;
    ushort2 v = *(const ushort2*)(XQKV + (size_t)(b * 2048 + s) * 6144 + 5120 +
                                  kvh * 128 + 2 * l);
    float c = fc[s * 64 + l], sn = fs[s * 64 + l];
    float xr = b2f(v.x), xi = b2f(v.y);
    Vl[2 * l][ss] = f2b(xr * c - xi * sn);
    Vl[2 * l + 1][ss] = f2b(xr * sn + xi * c);
  }
  __syncthreads();
  const int d = t >> 1, half = t & 1;
  unsigned short* vdst = Vt + ((size_t)bkv * 128 + d) * 2048 + s0 + half * 32;
#pragma unroll
  for (int e = 0; e < 32; e += 4) {
    ushort4 pk;
    pk.x = Vl[d][half * 32 + e];
    pk.y = Vl[d][half * 32 + e + 1];
    pk.z = Vl[d][half * 32 + e + 2];
    pk.w = Vl[d][half * 32 + e + 3];
    *(ushort4*)(vdst + e) = pk;
  }
}

// ---------------------------------------------------------------------------
// Flash attention (round-10/11 kernel, unchanged). Grid 512; 4 waves x 64 q.
__global__ __launch_bounds__(256, 2) void attn_fwd(
    const unsigned short* __restrict__ XQ, const unsigned short* __restrict__ Kr,
    const unsigned short* __restrict__ Vt, unsigned short* __restrict__ AO) {
  extern __shared__ char smem[];  // 49152
  char* Ksm = smem;                                      // [2][8192]
  char* Vsm = smem + 16384;                              // [2][8192]
  unsigned short* Ps = (unsigned short*)(smem + 32768);  // [4][4][64][8]
  const int t = threadIdx.x;
  const int lane = t & 63, w = t >> 6;
  const int lr = lane & 15, lg = lane >> 4;

  const int bid = blockIdx.x;
  const int nwg = gridDim.x;  // 512
  const int swz = (bid & 7) * (nwg >> 3) + (bid >> 3);
  const int qt = swz & 7;
  const int bh = swz >> 3;
  const int b = bh >> 5, h = bh & 31;
  const int bkv = b * 8 + (h >> 2);

  bf16x8 qf[4][4];
#pragma unroll
  for (int q4 = 0; q4 < 4; ++q4) {
    const unsigned short* qp =
        XQ + ((size_t)(b * 2048 + qt * 256 + w * 64 + q4 * 16 + lr)) * 6144 +
        h * 128 + lg * 8;
#pragma unroll
    for (int dc = 0; dc < 4; ++dc) qf[q4][dc] = *(const bf16x8*)(qp + dc * 32);
  }

  f32x4 acc[4][8];
#pragma unroll
  for (int q4 = 0; q4 < 4; ++q4)
#pragma unroll
    for (int i = 0; i < 8; ++i) acc[q4][i] = (f32x4){0.f, 0.f, 0.f, 0.f};
  float l_[4][4];
#pragma unroll
  for (int q4 = 0; q4 < 4; ++q4)
#pragma unroll
    for (int r = 0; r < 4; ++r) l_[q4][r] = 0.f;

  const unsigned short* Kbase = Kr + (size_t)bkv * 2048 * 128;
  const unsigned short* Vbase = Vt + (size_t)bkv * 128 * 2048;

  const int c0 = t, c1 = t + 256;
  const int kK0 = c0 & 31, dC0 = c0 >> 5;
  const int kK1 = c1 & 31, dC1 = c1 >> 5;
  const int vD0 = c0 & 127, vKc0 = c0 >> 7;
  const int vD1 = c1 & 127, vKc1 = c1 >> 7;
  const int dstb0 = (c0 & ~63) * 16;
  const int dstb1 = (c1 & ~63) * 16;

#define STAGE_KV(bufi, kt)                                                     \
  {                                                                            \
    char* kd = Ksm + (bufi)*8192;                                              \
    char* vd = Vsm + (bufi)*8192;                                              \
    load16(Kbase + (size_t)((kt)*32 + kK0) * 128 + dC0 * 8, kd + dstb0);       \
    load16(Kbase + (size_t)((kt)*32 + kK1) * 128 + dC1 * 8, kd + dstb1);       \
    load16(Vbase + (size_t)vD0 * 2048 + (kt)*32 + vKc0 * 8, vd + dstb0);       \
    load16(Vbase + (size_t)vD1 * 2048 + (kt)*32 + vKc1 * 8, vd + dstb1);       \
  }

  STAGE_KV(0, 0);
  asm volatile("s_waitcnt vmcnt(0)" ::: "memory");
  __builtin_amdgcn_s_barrier();

  unsigned short* Pw = Ps + w * 2048;              // [4 kc][64 q][8]
  const int pbase = (lr >> 3) * 512 + (lr & 7);    // halfword offset

  for (int kt = 0; kt < 64; ++kt) {
    const int cur = kt & 1;
    if (kt < 63) STAGE_KV(cur ^ 1, kt + 1);

    const char* Kc = Ksm + cur * 8192;
    const char* Vc = Vsm + cur * 8192;

#pragma unroll
    for (int nf = 0; nf < 2; ++nf) {
      f32x4 s[4];
#pragma unroll
      for (int q4 = 0; q4 < 4; ++q4) s[q4] = (f32x4){0.f, 0.f, 0.f, 0.f};
#pragma unroll
      for (int dc = 0; dc < 4; ++dc) {
        bf16x8 kf =
            *(const bf16x8*)(Kc + ((dc * 4 + lg) * 32 + nf * 16 + lr) * 16);
#pragma unroll
        for (int q4 = 0; q4 < 4; ++q4) s[q4] = mfma16(qf[q4][dc], kf, s[q4]);
      }
      const int pb = pbase + nf * 1024;  // kc = nf*2 + (lr>>3)
#pragma unroll
      for (int q4 = 0; q4 < 4; ++q4)
#pragma unroll
        for (int r = 0; r < 4; ++r) {
          float p = __builtin_amdgcn_exp2f(s[q4][r]);
          l_[q4][r] += p;
          Pw[pb + (q4 * 16 + lg * 4 + r) * 8] = f2b_fast(p);
        }
    }

    bf16x8 pf[4];
#pragma unroll
    for (int q4 = 0; q4 < 4; ++q4)
      pf[q4] = *(const bf16x8*)(Pw + lg * 512 + (q4 * 16 + lr) * 8);
#pragma unroll
    for (int dt = 0; dt < 8; ++dt) {
      bf16x8 vf = *(const bf16x8*)(Vc + (lg * 128 + dt * 16 + lr) * 16);
#pragma unroll
      for (int q4 = 0; q4 < 4; ++q4)
        acc[q4][dt] = mfma16(pf[q4], vf, acc[q4][dt]);
    }

    asm volatile("s_waitcnt vmcnt(0)" ::: "memory");
    __builtin_amdgcn_s_barrier();
  }
#undef STAGE_KV

#pragma unroll
  for (int q4 = 0; q4 < 4; ++q4)
#pragma unroll
    for (int r = 0; r < 4; ++r) {
#pragma unroll
      for (int o = 1; o < 16; o <<= 1) l_[q4][r] += __shfl_xor(l_[q4][r], o);
    }

#pragma unroll
  for (int q4 = 0; q4 < 4; ++q4)
#pragma unroll
    for (int r = 0; r < 4; ++r) {
      float inv = 1.f / l_[q4][r];
      size_t rowb =
          ((size_t)(b * 2048 + qt * 256 + w * 64 + q4 * 16 + lg * 4 + r)) * 4096 +
          h * 128;
#pragma unroll
      for (int dt = 0; dt < 8; ++dt)
        AO[rowb + dt * 16 + lr] = f2b_fast(acc[q4][dt][r] * inv);
    }
}

// ---------------------------------------------------------------------------
extern "C" void kernel_launch(void* const* d_in, const int* in_sizes, int n_in,
                              void* d_out, int out_size, void* d_ws, size_t ws_size,
                              hipStream_t stream) {
  const float* x  = (const float*)d_in[0];
  const float* fc = (const float*)d_in[2];
  const float* fs = (const float*)d_in[3];
  const float* wq = (const float*)d_in[4];
  const float* wk = (const float*)d_in[5];
  const float* wv = (const float*)d_in[6];
  const float* wo = (const float*)d_in[7];

  const size_t MB = 1024ull * 1024ull;
  char* ws = (char*)d_ws;
  unsigned short* Xb   = (unsigned short*)(ws);           // 32MB, dead after QKV gemm
  unsigned short* Wsc  = (unsigned short*)(ws + 32 * MB); // 48MB (wq|wk|wv), later wo
  unsigned short* Kr   = (unsigned short*)(ws);           // [0,8) reuse Xb
  unsigned short* Vt   = (unsigned short*)(ws + 8 * MB);  // [8,16)
  unsigned short* AO   = (unsigned short*)(ws + 80 * MB); // 32MB
  unsigned short* XQKV = (unsigned short*)d_out;          // 48MB of 64MB d_out

  (void)hipFuncSetAttribute((const void*)gemm128<unsigned short>,
                            hipFuncAttributeMaxDynamicSharedMemorySize, 98304);
  (void)hipFuncSetAttribute((const void*)gemm256<float>,
                            hipFuncAttributeMaxDynamicSharedMemorySize, 131072);
  (void)hipFuncSetAttribute((const void*)attn_fwd,
                            hipFuncAttributeMaxDynamicSharedMemorySize, 49152);

  dim3 blk(256);
  dim3 blk512(512);
  cvt_f32_bf16<<<2048, blk, 0, stream>>>(x, Xb, (2 * 2048 * 4096) / 4);
  cvt_w3<<<2048, blk, 0, stream>>>(wq, wk, wv, Wsc);
  gemm128<unsigned short><<<768, blk512, 98304, stream>>>(
      Xb, Wsc, XQKV, 4096, 6144, 4096, /*sbl=*/16);
  rope_kv<<<512, blk, 0, stream>>>(XQKV, fc, fs, Kr, Vt);
  attn_fwd<<<512, blk, 49152, stream>>>(XQKV, Kr, Vt, AO);
  cvt_f32_bf16<<<2048, blk, 0, stream>>>(wo, Wsc, (4096 * 4096) / 4);
  gemm256<float><<<256, blk512, 131072, stream>>>(
      AO, Wsc, (float*)d_out, 4096, 4096, 4096, /*sbl=*/0);
}